// Round 5
// baseline (10862.060 us; speedup 1.0000x reference)
//
#include <hip/hip_runtime.h>
#include <hip/hip_bf16.h>

// ---------------------------------------------------------------------------
// StyleEncoder fused fp32 pipeline for MI355X (gfx950).
// All inputs fp32; d_out fp32:
//   out[16*256*512] @0, vq_loss @2097152, idx (as float) @2097153.
// B=16, T=2048, L=512, H=256, 2H=512, KS=3, CVQ=64, K=128, NL*NB=10.
// R5: producer-computed LN stats (MM/IV per (b,t)) -> conv1/lnconv stage
//     128-channel LN'd chunks (34 KB LDS) + p-split over blockIdx.z
//     -> 4 blocks/CU (was 2).
// ---------------------------------------------------------------------------

#define OUT_LOSS_OFF 2097152
#define OUT_IDX_OFF  2097153

// ---------------- weight transposes ----------------------------------------
// w [G][O][Cin][3] -> wt [G][Cin*3][O]
__global__ __launch_bounds__(256) void k_t_conv3(const float* __restrict__ w,
                                                 float* __restrict__ wt,
                                                 int G, int O, int Cin) {
    size_t n = (size_t)G * O * Cin * 3;
    for (size_t i = (size_t)blockIdx.x * 256 + threadIdx.x; i < n;
         i += (size_t)gridDim.x * 256) {
        int k = (int)(i % 3);
        size_t r = i / 3;
        int c = (int)(r % Cin); r /= Cin;
        int o = (int)(r % O);
        int g = (int)(r / O);
        wt[((size_t)g * Cin * 3 + (size_t)(c * 3 + k)) * O + o] = w[i];
    }
}

// w [G][O][I] -> wt [G][I][O]
__global__ __launch_bounds__(256) void k_t_mat(const float* __restrict__ w,
                                               float* __restrict__ wt,
                                               int G, int O, int I) {
    size_t n = (size_t)G * O * I;
    for (size_t i = (size_t)blockIdx.x * 256 + threadIdx.x; i < n;
         i += (size_t)gridDim.x * 256) {
        int ci = (int)(i % I);
        int o  = (int)((i / I) % O);
        int g  = (int)(i / ((size_t)I * O));
        wt[((size_t)g * I + ci) * O + o] = w[i];
    }
}

// ---------------- pointwise conv (+ optional column stats) ------------------
// y[b,o,t] = sum_i wt[i][o]*x[b,i,t] + bias[o]  (optional *mask[b,t])
// STATS: also emit per-(b,t) mean / rsqrt(var) over the COUT channels.
template <int CIN, int COUT, int CHUNK, bool STATS>
__global__ __launch_bounds__(256) void k_pw(const float* __restrict__ x,
                                            const float* __restrict__ wt,
                                            const float* __restrict__ bias,
                                            const float* __restrict__ mask,
                                            float* __restrict__ y,
                                            float* __restrict__ MM,
                                            float* __restrict__ IV, int T) {
    extern __shared__ float X[];  // [CIN][64]
    constexpr int NG = COUT / CHUNK;
    __shared__ float rs[64 * NG], rs2[64 * NG];
    const int b = blockIdx.y, t0 = blockIdx.x * 64;
    for (int i = threadIdx.x; i < CIN * 64; i += 256) {
        int ci = i >> 6, j = i & 63;
        X[i] = x[((size_t)b * CIN + ci) * T + t0 + j];
    }
    __syncthreads();
    const int tl = threadIdx.x & 63;
    const int g = __builtin_amdgcn_readfirstlane((int)(threadIdx.x >> 6));
    float acc[CHUNK];
#pragma unroll
    for (int o = 0; o < CHUNK; o++) acc[o] = 0.f;
    for (int i = 0; i < CIN; i++) {
        float xv = X[i * 64 + tl];
        const float* wr = wt + (size_t)i * COUT + g * CHUNK;  // wave-uniform
#pragma unroll
        for (int o = 0; o < CHUNK; o++) acc[o] = fmaf(wr[o], xv, acc[o]);
    }
    float mk = mask ? mask[(size_t)b * T + t0 + tl] : 1.0f;
    float s = 0.f, s2 = 0.f;
#pragma unroll
    for (int o = 0; o < CHUNK; o++) {
        int oc = g * CHUNK + o;
        float val = (acc[o] + bias[oc]) * mk;
        y[((size_t)b * COUT + oc) * T + t0 + tl] = val;
        s += val; s2 += val * val;
    }
    if constexpr (STATS) {
        rs[g * 64 + tl] = s; rs2[g * 64 + tl] = s2;
        __syncthreads();
        if (threadIdx.x < 64) {
            float ss = 0.f, ss2 = 0.f;
#pragma unroll
            for (int gg = 0; gg < NG; gg++) {
                ss += rs[gg * 64 + threadIdx.x];
                ss2 += rs2[gg * 64 + threadIdx.x];
            }
            float m = ss * (1.0f / COUT);
            float var = ss2 * (1.0f / COUT) - m * m;
            MM[(size_t)b * T + t0 + threadIdx.x] = m;
            IV[(size_t)b * T + t0 + threadIdx.x] = 1.0f / sqrtf(var + 1e-5f);
        }
    }
}

// ---------------- sub-block part 1: LN + causal conv(256->512) + GELU -------
// blockIdx.z = p selects output half [p*256, p*256+256).
// Stats precomputed by producer (MM/IV). 34 KB LDS -> 4 blocks/CU.
__global__ __launch_bounds__(512, 8) void k_conv1(
    const float* __restrict__ xin, float* __restrict__ gout,
    const float* __restrict__ MM, const float* __restrict__ IV,
    const float* __restrict__ lng, const float* __restrict__ lnb,
    const float* __restrict__ w1t, const float* __restrict__ b1, int T) {
    __shared__ float CH[128 * 66];
    __shared__ float sm_m[66], sm_v[66];
    const int b = blockIdx.y, t0 = blockIdx.x * 64, p = blockIdx.z;
    const size_t xoff = (size_t)b * 256 * T;
    if (threadIdx.x < 66) {
        int t = t0 - 2 + (int)threadIdx.x;
        sm_m[threadIdx.x] = (t >= 0) ? MM[(size_t)b * T + t] : 0.f;
        sm_v[threadIdx.x] = (t >= 0) ? IV[(size_t)b * T + t] : 0.f;
    }
    const int tl = threadIdx.x & 63;
    const int g = __builtin_amdgcn_readfirstlane((int)(threadIdx.x >> 6));
    float acc[32];
#pragma unroll
    for (int o = 0; o < 32; o++) acc[o] = 0.f;
    const float* w1p = w1t + (p * 256 + g * 32);  // wave-uniform col offset

    for (int ch = 0; ch < 2; ch++) {
        __syncthreads();  // sm_m ready (ch=0) / CH consumers done (ch=1)
        for (int i = threadIdx.x; i < 128 * 66; i += 512) {
            int c = i / 66, j = i - c * 66;
            int t = t0 - 2 + j;
            int cc = ch * 128 + c;
            float val = 0.f;
            if (t >= 0)
                val = (xin[xoff + (size_t)cc * T + t] - sm_m[j]) * sm_v[j] *
                          lng[cc] + lnb[cc];
            CH[i] = val;  // causal zero-pad for t<0
        }
        __syncthreads();
        for (int c = 0; c < 128; ++c) {
#pragma unroll
            for (int k = 0; k < 3; ++k) {
                float xv = CH[c * 66 + tl + k];
                const float* wr = w1p + (size_t)((ch * 128 + c) * 3 + k) * 512;
#pragma unroll
                for (int o = 0; o < 32; o++) acc[o] = fmaf(wr[o], xv, acc[o]);
            }
        }
    }
    const float kscale = 0.5773502691896258f;  // 3^-0.5
    const size_t goff = (size_t)b * 512 * T;
#pragma unroll
    for (int o = 0; o < 32; o++) {
        int oc = p * 256 + g * 32 + o;
        float y = (acc[o] + b1[oc]) * kscale;
        float ge = 0.5f * y * (1.0f + erff(y * 0.7071067811865476f));
        gout[goff + (size_t)oc * T + t0 + tl] = ge;
    }
}

// ---------------- sub-block part 2: 1x1 conv(512->256) + residual + stats ---
// xout = (xin + W2*gin + b2) * mask; emits LN stats of xout for next layer.
__global__ __launch_bounds__(512, 8) void k_conv2(
    const float* __restrict__ gin,   // [b][512][T]
    const float* __restrict__ xin, float* __restrict__ xout,
    const float* __restrict__ w2t,   // [512][256]
    const float* __restrict__ b2,
    const float* __restrict__ mask,
    float* __restrict__ MM, float* __restrict__ IV, int T) {
    __shared__ float S[128 * 64];    // 32 KB
    __shared__ float rs[512], rs2[512];
    const int b = blockIdx.y, t0 = blockIdx.x * 64;
    const int tl = threadIdx.x & 63;
    const int g = __builtin_amdgcn_readfirstlane((int)(threadIdx.x >> 6));
    const size_t goff = (size_t)b * 512 * T;

    float acc[32];
#pragma unroll
    for (int o = 0; o < 32; o++) acc[o] = 0.f;

    for (int ch = 0; ch < 4; ch++) {
        __syncthreads();
        float4* S4 = (float4*)S;
        for (int i = threadIdx.x; i < 2048; i += 512) {  // 128 rows x 16 f4
            int r = i >> 4, cq = i & 15;
            S4[i] = *(const float4*)&gin[goff + (size_t)(ch * 128 + r) * T +
                                         t0 + cq * 4];
        }
        __syncthreads();
        const float* w2p = w2t + (size_t)(ch * 128) * 256 + g * 32;
        for (int r = 0; r < 128; ++r) {
            float xv = S[r * 64 + tl];
            const float* wr = w2p + (size_t)r * 256;
#pragma unroll
            for (int o = 0; o < 32; o++) acc[o] = fmaf(wr[o], xv, acc[o]);
        }
    }
    const size_t xoff = (size_t)b * 256 * T;
    float mk = mask[(size_t)b * T + t0 + tl];
    float s = 0.f, s2 = 0.f;
#pragma unroll
    for (int o = 0; o < 32; o++) {
        int oc = g * 32 + o;
        size_t adr = xoff + (size_t)oc * T + t0 + tl;
        float val = (xin[adr] + acc[o] + b2[oc]) * mk;
        xout[adr] = val;
        s += val; s2 += val * val;
    }
    rs[g * 64 + tl] = s; rs2[g * 64 + tl] = s2;
    __syncthreads();
    if (threadIdx.x < 64) {
        float ss = 0.f, ss2 = 0.f;
#pragma unroll
        for (int gg = 0; gg < 8; gg++) {
            ss += rs[gg * 64 + threadIdx.x];
            ss2 += rs2[gg * 64 + threadIdx.x];
        }
        float m = ss * (1.0f / 256.0f);
        float var = ss2 * (1.0f / 256.0f) - m * m;
        MM[(size_t)b * T + t0 + threadIdx.x] = m;
        IV[(size_t)b * T + t0 + threadIdx.x] = 1.0f / sqrtf(var + 1e-5f);
    }
}

// ---------------- final LN*mask + causal conv (k=3, 256->256) ---------------
__global__ __launch_bounds__(512, 8) void k_lnconv(
    const float* __restrict__ xin, float* __restrict__ xout,
    const float* __restrict__ MM, const float* __restrict__ IV,
    const float* __restrict__ lg, const float* __restrict__ lb,
    const float* __restrict__ wt, const float* __restrict__ bias,
    const float* __restrict__ mask, int T) {
    __shared__ float CH[128 * 66];
    __shared__ float sm_m[66], sm_v[66], sm_k[66];
    const int b = blockIdx.y, t0 = blockIdx.x * 64;
    const size_t xoff = (size_t)b * 256 * T;
    if (threadIdx.x < 66) {
        int t = t0 - 2 + (int)threadIdx.x;
        sm_m[threadIdx.x] = (t >= 0) ? MM[(size_t)b * T + t] : 0.f;
        sm_v[threadIdx.x] = (t >= 0) ? IV[(size_t)b * T + t] : 0.f;
        sm_k[threadIdx.x] = (t >= 0) ? mask[(size_t)b * T + t] : 0.f;
    }
    const int tl = threadIdx.x & 63;
    const int g = __builtin_amdgcn_readfirstlane((int)(threadIdx.x >> 6));
    float acc[32];
#pragma unroll
    for (int o = 0; o < 32; o++) acc[o] = 0.f;
    const float* wp = wt + g * 32;

    for (int ch = 0; ch < 2; ch++) {
        __syncthreads();
        for (int i = threadIdx.x; i < 128 * 66; i += 512) {
            int c = i / 66, j = i - c * 66;
            int t = t0 - 2 + j;
            int cc = ch * 128 + c;
            float val = 0.f;
            if (t >= 0)
                val = ((xin[xoff + (size_t)cc * T + t] - sm_m[j]) * sm_v[j] *
                           lg[cc] + lb[cc]) * sm_k[j];
            CH[i] = val;
        }
        __syncthreads();
        for (int c = 0; c < 128; ++c) {
#pragma unroll
            for (int k = 0; k < 3; ++k) {
                float xv = CH[c * 66 + tl + k];
                const float* wr = wp + (size_t)((ch * 128 + c) * 3 + k) * 256;
#pragma unroll
                for (int o = 0; o < 32; o++) acc[o] = fmaf(wr[o], xv, acc[o]);
            }
        }
    }
    float mk = mask[(size_t)b * T + t0 + tl];
#pragma unroll
    for (int o = 0; o < 32; o++) {
        int oc = g * 32 + o;
        xout[xoff + (size_t)oc * T + t0 + tl] = (acc[o] + bias[oc]) * mk;
    }
}

// ---------------- group-by-segments (scatter mean) --------------------------
__global__ __launch_bounds__(256) void k_counts(const int* __restrict__ m2p,
                                                int* __restrict__ cnt) {
    __shared__ int c[512];
    int b = blockIdx.x;
    for (int i = threadIdx.x; i < 512; i += 256) c[i] = 0;
    __syncthreads();
    for (int t = threadIdx.x; t < 2048; t += 256) {
        int p = m2p[b * 2048 + t];
        if (p >= 1 && p <= 512) atomicAdd(&c[p - 1], 1);
    }
    __syncthreads();
    for (int i = threadIdx.x; i < 512; i += 256) cnt[b * 512 + i] = c[i];
}

__global__ __launch_bounds__(256) void k_scatter(const float* __restrict__ h,
                                                 const int* __restrict__ m2p,
                                                 float* __restrict__ g) {
    extern __shared__ float sm[];
    float* HT = sm;                    // 256*65 (padded)
    int* ph = (int*)(sm + 256 * 65);   // 64
    int b = blockIdx.y, t0 = blockIdx.x * 64;
    if (threadIdx.x < 64) ph[threadIdx.x] = m2p[b * 2048 + t0 + threadIdx.x];
    for (int i = threadIdx.x; i < 256 * 64; i += 256) {
        int c = i >> 6, j = i & 63;
        HT[c * 65 + j] = h[((size_t)b * 256 + c) * 2048 + t0 + j];
    }
    __syncthreads();
    int c = threadIdx.x;
    float run = 0.f;
    int cur = ph[0];
    for (int j = 0; j < 64; j++) {
        int p = ph[j];
        if (p != cur) {
            if (cur >= 1 && cur <= 512)
                atomicAdd(&g[((size_t)b * 256 + c) * 512 + cur - 1], run);
            run = 0.f;
            cur = p;
        }
        run += HT[c * 65 + j];
    }
    if (cur >= 1 && cur <= 512)
        atomicAdd(&g[((size_t)b * 256 + c) * 512 + cur - 1], run);
}

// divide by counts + emit LN stats for postnet layer 0 (T=512)
__global__ __launch_bounds__(512) void k_postprep(float* __restrict__ g,
                                                  const int* __restrict__ cnt,
                                                  float* __restrict__ MM,
                                                  float* __restrict__ IV) {
    int b = blockIdx.x, l = threadIdx.x;
    int c1 = cnt[b * 512 + l];
    if (c1 < 1) c1 = 1;
    float rc = 1.0f / (float)c1;
    float s = 0.f, s2 = 0.f;
    for (int c = 0; c < 256; c++) {
        size_t idx = ((size_t)b * 256 + c) * 512 + l;
        float v = g[idx] * rc;
        g[idx] = v;
        s += v; s2 += v * v;
    }
    float m = s * (1.0f / 256.0f);
    float var = s2 * (1.0f / 256.0f) - m * m;
    MM[(size_t)b * 512 + l] = m;
    IV[(size_t)b * 512 + l] = 1.0f / sqrtf(var + 1e-5f);
}

// ---------------- VQ --------------------------------------------------------
__global__ __launch_bounds__(256) void k_vq(const float* __restrict__ z,
                                            const float* __restrict__ cb,
                                            int* __restrict__ idxout,
                                            float* __restrict__ out,
                                            float* __restrict__ lossacc) {
    int n = blockIdx.x * 256 + threadIdx.x;  // 0..8191
    int b = n >> 9, l = n & 511;
    float zr[64];
#pragma unroll
    for (int c = 0; c < 64; c++) zr[c] = z[((size_t)b * 64 + c) * 512 + l];
    float best = 3.4e38f;
    int bi = 0;
    for (int k = 0; k < 128; k++) {
        const float* cr = cb + k * 64;  // uniform -> s_load
        float d = 0.f;
#pragma unroll
        for (int c = 0; c < 64; c++) {
            float t = zr[c] - cr[c];
            d = fmaf(t, t, d);
        }
        if (d < best) { best = d; bi = k; }  // strict < == np first-argmin
    }
    idxout[n] = bi;
    out[OUT_IDX_OFF + n] = (float)bi;
    atomicAdd(lossacc, best);
}

__global__ void k_loss(const float* __restrict__ acc,
                       float* __restrict__ out) {
    if (threadIdx.x == 0 && blockIdx.x == 0)
        out[OUT_LOSS_OFF] = 0.25f * acc[0] * (1.0f / 524288.0f);
}

// ---------------- proj_out (q = codebook[idx]) ------------------------------
__global__ __launch_bounds__(256) void k_projout(const float* __restrict__ cb,
                                                 const int* __restrict__ idx,
                                                 const float* __restrict__ wt,
                                                 const float* __restrict__ bias,
                                                 float* __restrict__ out) {
    __shared__ float Q[64 * 64];  // [c][l]
    __shared__ int ids[64];
    int b = blockIdx.y, l0 = blockIdx.x * 64;
    if (threadIdx.x < 64) ids[threadIdx.x] = idx[b * 512 + l0 + threadIdx.x];
    __syncthreads();
    for (int i = threadIdx.x; i < 4096; i += 256) {
        int c = i >> 6, l = i & 63;
        Q[c * 64 + l] = cb[ids[l] * 64 + c];
    }
    __syncthreads();
    int tl = threadIdx.x & 63;
    int g = __builtin_amdgcn_readfirstlane((int)(threadIdx.x >> 6));
    float acc[64];
#pragma unroll
    for (int o = 0; o < 64; o++) acc[o] = 0.f;
    for (int i = 0; i < 64; i++) {
        float xv = Q[i * 64 + tl];
        const float* wr = wt + i * 256 + g * 64;
#pragma unroll
        for (int o = 0; o < 64; o++) acc[o] = fmaf(wr[o], xv, acc[o]);
    }
#pragma unroll
    for (int o = 0; o < 64; o++) {
        int oc = g * 64 + o;
        out[(size_t)b * 131072 + (size_t)oc * 512 + l0 + tl] = acc[o] + bias[oc];
    }
}

// ---------------------------------------------------------------------------
extern "C" void kernel_launch(void* const* d_in, const int* in_sizes, int n_in,
                              void* d_out, int out_size, void* d_ws, size_t ws_size,
                              hipStream_t stream) {
    (void)in_sizes; (void)n_in; (void)out_size; (void)ws_size;
    const float* x          = (const float*)d_in[0];
    const float* in_np      = (const float*)d_in[1];
    const int*   mel2ph     = (const int*)d_in[2];
    const float* ph_np      = (const float*)d_in[3];
    const float* conv_in_w  = (const float*)d_in[4];
    const float* conv_in_b  = (const float*)d_in[5];
    const float* e_ln_g = (const float*)d_in[6];
    const float* e_ln_b = (const float*)d_in[7];
    const float* e_w1   = (const float*)d_in[8];
    const float* e_b1   = (const float*)d_in[9];
    const float* e_w2   = (const float*)d_in[10];
    const float* e_b2   = (const float*)d_in[11];
    const float* e_lg   = (const float*)d_in[12];
    const float* e_lb   = (const float*)d_in[13];
    const float* e_pw   = (const float*)d_in[14];
    const float* e_pb   = (const float*)d_in[15];
    const float* p_ln_g = (const float*)d_in[16];
    const float* p_ln_b = (const float*)d_in[17];
    const float* p_w1   = (const float*)d_in[18];
    const float* p_b1   = (const float*)d_in[19];
    const float* p_w2   = (const float*)d_in[20];
    const float* p_b2   = (const float*)d_in[21];
    const float* p_lg   = (const float*)d_in[22];
    const float* p_lb   = (const float*)d_in[23];
    const float* p_pw   = (const float*)d_in[24];
    const float* p_pb   = (const float*)d_in[25];
    const float* proj_in_w  = (const float*)d_in[26];
    const float* proj_in_b  = (const float*)d_in[27];
    const float* proj_out_w = (const float*)d_in[28];
    const float* proj_out_b = (const float*)d_in[29];
    const float* codebook   = (const float*)d_in[30];
    float* out = (float*)d_out;

    float* ws = (float*)d_ws;
    float* A      = ws;                        // 16*256*2048 = 8388608
    float* Bb     = A + 8388608;               // 8388608
    float* W1T_E  = Bb + 8388608;              // 10*768*512 = 3932160
    float* W1T_P  = W1T_E + 3932160;
    float* W2T_E  = W1T_P + 3932160;           // 10*512*256 = 1310720
    float* W2T_P  = W2T_E + 1310720;
    float* CINT   = W2T_P + 1310720;           // 80*256
    float* PSTT_E = CINT + 20480;              // 768*256
    float* PSTT_P = PSTT_E + 196608;
    float* PINT   = PSTT_P + 196608;           // 256*64
    float* POUTT  = PINT + 16384;              // 64*256
    float* Z      = POUTT + 16384;             // 16*64*512 = 524288
    int*   CNT    = (int*)(Z + 524288);        // 8192
    int*   IDX    = CNT + 8192;                // 8192
    float* LOSS   = (float*)(IDX + 8192);      // 1
    float* MM     = LOSS + 1;                  // 16*2048 = 32768
    float* IV     = MM + 32768;                // 32768
    float* CTG    = IV + 32768;                // 16*512*2048 = 16777216

    // weight transposes (d_ws is re-poisoned every call -> recompute)
    k_t_conv3<<<dim3(2048), dim3(256), 0, stream>>>(e_w1, W1T_E, 10, 512, 256);
    k_t_conv3<<<dim3(2048), dim3(256), 0, stream>>>(p_w1, W1T_P, 10, 512, 256);
    k_t_mat  <<<dim3(1024), dim3(256), 0, stream>>>(e_w2, W2T_E, 10, 256, 512);
    k_t_mat  <<<dim3(1024), dim3(256), 0, stream>>>(p_w2, W2T_P, 10, 256, 512);
    k_t_mat  <<<dim3(80),   dim3(256), 0, stream>>>(conv_in_w, CINT, 1, 256, 80);
    k_t_conv3<<<dim3(768),  dim3(256), 0, stream>>>(e_pw, PSTT_E, 1, 256, 256);
    k_t_conv3<<<dim3(768),  dim3(256), 0, stream>>>(p_pw, PSTT_P, 1, 256, 256);
    k_t_mat  <<<dim3(64),   dim3(256), 0, stream>>>(proj_in_w, PINT, 1, 64, 256);
    k_t_mat  <<<dim3(64),   dim3(256), 0, stream>>>(proj_out_w, POUTT, 1, 256, 64);

    const size_t sm_scat = 256 * 65 * sizeof(float) + 64 * sizeof(int);

    // ---- conv_in + mask -> A (+ LN stats for encoder layer 0)
    k_pw<80, 256, 64, true><<<dim3(32, 16), dim3(256), 80 * 64 * 4, stream>>>(
        x, CINT, conv_in_b, in_np, A, MM, IV, 2048);

    // ---- encoder: 10 sub-blocks, ping-pong A<->B (ends in A)
    float* cur = A;
    float* nxt = Bb;
    for (int s = 0; s < 10; s++) {
        k_conv1<<<dim3(32, 16, 2), dim3(512), 0, stream>>>(
            cur, CTG, MM, IV, e_ln_g + s * 256, e_ln_b + s * 256,
            W1T_E + (size_t)s * 768 * 512, e_b1 + s * 512, 2048);
        k_conv2<<<dim3(32, 16), dim3(512), 0, stream>>>(
            CTG, cur, nxt, W2T_E + (size_t)s * 512 * 256, e_b2 + s * 256,
            in_np, MM, IV, 2048);
        float* t = cur; cur = nxt; nxt = t;
    }
    // ---- final LN + post conv: A -> B
    k_lnconv<<<dim3(32, 16), dim3(512), 0, stream>>>(
        cur, nxt, MM, IV, e_lg, e_lb, PSTT_E, e_pb, in_np, 2048);

    // ---- group-by-segs: B (T=2048) -> A (compact [16,256,512])
    hipMemsetAsync(A, 0, (size_t)2097152 * 4, stream);
    hipMemsetAsync(LOSS, 0, 4, stream);
    k_counts<<<dim3(16), dim3(256), 0, stream>>>(mel2ph, CNT);
    k_scatter<<<dim3(32, 16), dim3(256), sm_scat, stream>>>(Bb, mel2ph, A);
    k_postprep<<<dim3(16), dim3(512), 0, stream>>>(A, CNT, MM, IV);

    // ---- postnet: 10 sub-blocks on T=512, ping-pong (ends in A)
    cur = A; nxt = Bb;
    for (int s = 0; s < 10; s++) {
        k_conv1<<<dim3(8, 16, 2), dim3(512), 0, stream>>>(
            cur, CTG, MM, IV, p_ln_g + s * 256, p_ln_b + s * 256,
            W1T_P + (size_t)s * 768 * 512, p_b1 + s * 512, 512);
        k_conv2<<<dim3(8, 16), dim3(512), 0, stream>>>(
            CTG, cur, nxt, W2T_P + (size_t)s * 512 * 256, p_b2 + s * 256,
            ph_np, MM, IV, 512);
        float* t = cur; cur = nxt; nxt = t;
    }
    k_lnconv<<<dim3(8, 16), dim3(512), 0, stream>>>(
        cur, nxt, MM, IV, p_lg, p_lb, PSTT_P, p_pb, ph_np, 512);

    // ---- proj_in: B -> Z [16,64,512]
    k_pw<256, 64, 16, false><<<dim3(8, 16), dim3(256), 256 * 64 * 4, stream>>>(
        Bb, PINT, proj_in_b, nullptr, Z, nullptr, nullptr, 512);

    // ---- VQ + loss + proj_out
    k_vq<<<dim3(32), dim3(256), 0, stream>>>(Z, codebook, IDX, out, LOSS);
    k_loss<<<dim3(1), dim3(64), 0, stream>>>(LOSS, out);
    k_projout<<<dim3(8, 16), dim3(256), 0, stream>>>(codebook, IDX, POUTT,
                                                     proj_out_b, out);
}

// Round 7
// 7333.968 us; speedup vs baseline: 1.4811x; 1.4811x over previous
//
#include <hip/hip_runtime.h>
#include <hip/hip_bf16.h>

// ---------------------------------------------------------------------------
// StyleEncoder pipeline for MI355X (gfx950).  R7: conv1/conv2 as split-f16
// MFMA GEMMs (x=hi+lo, w=hi+lo in f16: 22-bit mantissa coverage, 3x
// mfma_f32_32x32x16_f16 -> ~2^-23 rel err per GEMM; bf16 split (R6) was
// 2^-16 and flipped a few VQ argmins).
// All inputs fp32; d_out fp32: out @0, vq_loss @2097152, idx @2097153.
// B=16, T=2048, L=512, H=256, 2H=512, KS=3, CVQ=64, K=128, NL*NB=10.
// ---------------------------------------------------------------------------

typedef unsigned short u16;
typedef unsigned int u32;
typedef __attribute__((ext_vector_type(8))) _Float16 f16x8;
typedef __attribute__((ext_vector_type(16))) float f32x16;

#define OUT_LOSS_OFF 2097152
#define OUT_IDX_OFF  2097153

__device__ __forceinline__ void split_f16(float x, u16& h, u16& l) {
    union { _Float16 f; u16 u; } a, b;
    a.f = (_Float16)x;              // RNE f32->f16
    float hf = (float)a.f;
    b.f = (_Float16)(x - hf);       // exact residual, RNE to f16
    h = a.u; l = b.u;
}

// ---------------- weight transposes (fp32 kept for lnconv/pw) ---------------
__global__ __launch_bounds__(256) void k_t_conv3(const float* __restrict__ w,
                                                 float* __restrict__ wt,
                                                 int G, int O, int Cin) {
    size_t n = (size_t)G * O * Cin * 3;
    for (size_t i = (size_t)blockIdx.x * 256 + threadIdx.x; i < n;
         i += (size_t)gridDim.x * 256) {
        int k = (int)(i % 3);
        size_t r = i / 3;
        int c = (int)(r % Cin); r /= Cin;
        int o = (int)(r % O);
        int g = (int)(r / O);
        wt[((size_t)g * Cin * 3 + (size_t)(c * 3 + k)) * O + o] = w[i];
    }
}

__global__ __launch_bounds__(256) void k_t_mat(const float* __restrict__ w,
                                               float* __restrict__ wt,
                                               int G, int O, int I) {
    size_t n = (size_t)G * O * I;
    for (size_t i = (size_t)blockIdx.x * 256 + threadIdx.x; i < n;
         i += (size_t)gridDim.x * 256) {
        int ci = (int)(i % I);
        int o  = (int)((i / I) % O);
        int g  = (int)(i / ((size_t)I * O));
        wt[((size_t)g * I + ci) * O + o] = w[i];
    }
}

// ---- W1 -> B-fragment layout, split hi/lo f16.
// idx = ((((s*3+k3)*16+kb)*16+nt)*64+L)*8+j ; val = w1[s][oc][c][k3]
// oc = nt*32+(L&31), c = kb*16+((L>>5)<<3)+j
__global__ __launch_bounds__(256) void k_t_w1mf(const float* __restrict__ w,
                                                u16* __restrict__ BH,
                                                u16* __restrict__ BL, int S) {
    size_t N = (size_t)S * 3 * 16 * 16 * 64 * 8;
    for (size_t i = (size_t)blockIdx.x * 256 + threadIdx.x; i < N;
         i += (size_t)gridDim.x * 256) {
        int j = (int)(i & 7); size_t r = i >> 3;
        int L = (int)(r & 63); r >>= 6;
        int nt = (int)(r & 15); r >>= 4;
        int kb = (int)(r & 15); r >>= 4;
        int k3 = (int)(r % 3); int s = (int)(r / 3);
        int oc = nt * 32 + (L & 31);
        int c = kb * 16 + ((L >> 5) << 3) + j;
        float v = w[(((size_t)s * 512 + oc) * 256 + c) * 3 + k3];
        u16 h, l; split_f16(v, h, l);
        BH[i] = h; BL[i] = l;
    }
}

// ---- W2 -> B-fragment layout. idx = (((s*32+kb)*8+nt)*64+L)*8+j
// val = w2[s][oc][ic], oc = nt*32+(L&31), ic = kb*16+((L>>5)<<3)+j
__global__ __launch_bounds__(256) void k_t_w2mf(const float* __restrict__ w,
                                                u16* __restrict__ BH,
                                                u16* __restrict__ BL, int S) {
    size_t N = (size_t)S * 32 * 8 * 64 * 8;
    for (size_t i = (size_t)blockIdx.x * 256 + threadIdx.x; i < N;
         i += (size_t)gridDim.x * 256) {
        int j = (int)(i & 7);
        int L = (int)((i >> 3) & 63);
        int nt = (int)((i >> 9) & 7);
        int kb = (int)((i >> 12) & 31);
        int s = (int)(i >> 17);
        int oc = nt * 32 + (L & 31);
        int ic = kb * 16 + ((L >> 5) << 3) + j;
        float v = w[((size_t)s * 256 + oc) * 512 + ic];
        u16 h, l; split_f16(v, h, l);
        BH[i] = h; BL[i] = l;
    }
}

// ---------------- pointwise conv (+ optional column stats) ------------------
template <int CIN, int COUT, int CHUNK, bool STATS>
__global__ __launch_bounds__(256) void k_pw(const float* __restrict__ x,
                                            const float* __restrict__ wt,
                                            const float* __restrict__ bias,
                                            const float* __restrict__ mask,
                                            float* __restrict__ y,
                                            float* __restrict__ MM,
                                            float* __restrict__ IV, int T) {
    extern __shared__ float X[];
    constexpr int NG = COUT / CHUNK;
    __shared__ float rs[64 * NG], rs2[64 * NG];
    const int b = blockIdx.y, t0 = blockIdx.x * 64;
    for (int i = threadIdx.x; i < CIN * 64; i += 256) {
        int ci = i >> 6, j = i & 63;
        X[i] = x[((size_t)b * CIN + ci) * T + t0 + j];
    }
    __syncthreads();
    const int tl = threadIdx.x & 63;
    const int g = __builtin_amdgcn_readfirstlane((int)(threadIdx.x >> 6));
    float acc[CHUNK];
#pragma unroll
    for (int o = 0; o < CHUNK; o++) acc[o] = 0.f;
    for (int i = 0; i < CIN; i++) {
        float xv = X[i * 64 + tl];
        const float* wr = wt + (size_t)i * COUT + g * CHUNK;
#pragma unroll
        for (int o = 0; o < CHUNK; o++) acc[o] = fmaf(wr[o], xv, acc[o]);
    }
    float mk = mask ? mask[(size_t)b * T + t0 + tl] : 1.0f;
    float s = 0.f, s2 = 0.f;
#pragma unroll
    for (int o = 0; o < CHUNK; o++) {
        int oc = g * CHUNK + o;
        float val = (acc[o] + bias[oc]) * mk;
        y[((size_t)b * COUT + oc) * T + t0 + tl] = val;
        s += val; s2 += val * val;
    }
    if constexpr (STATS) {
        rs[g * 64 + tl] = s; rs2[g * 64 + tl] = s2;
        __syncthreads();
        if (threadIdx.x < 64) {
            float ss = 0.f, ss2 = 0.f;
#pragma unroll
            for (int gg = 0; gg < NG; gg++) {
                ss += rs[gg * 64 + threadIdx.x];
                ss2 += rs2[gg * 64 + threadIdx.x];
            }
            float m = ss * (1.0f / COUT);
            float var = ss2 * (1.0f / COUT) - m * m;
            MM[(size_t)b * T + t0 + threadIdx.x] = m;
            IV[(size_t)b * T + t0 + threadIdx.x] = 1.0f / sqrtf(var + 1e-5f);
        }
    }
}

// ---------------- conv1: LN + causal conv(256->512) + GELU via MFMA ---------
// Block: 512 thr, tile M=64 t x N=512 oc, K = 3 shifts x 256 c.
// Wave w: mg=w&1 (m32-tile), ng=w>>1 (4 n32-tiles). Out: packed(hi,lo) u32.
__global__ __launch_bounds__(512, 4) void k_conv1(
    const float* __restrict__ xin, u32* __restrict__ G_P,
    const float* __restrict__ MM, const float* __restrict__ IV,
    const float* __restrict__ lng, const float* __restrict__ lnb,
    const u16* __restrict__ BH, const u16* __restrict__ BL,
    const float* __restrict__ b1, int T) {
    __shared__ u16 LH[66 * 264];
    __shared__ u16 LL[66 * 264];
    const int tid = threadIdx.x;
    const int b = blockIdx.y, t0 = blockIdx.x * 64;
    const size_t xoff = (size_t)b * 256 * T;
    // ---- stage: LN'd x, split hi/lo f16, layout [j 0..65][c 0..255]
    {
        int jj = tid & 63;
        int gg = tid >> 6;
        int t = t0 - 2 + jj;
        bool ok = (t >= 0);
        float m = ok ? MM[(size_t)b * T + t] : 0.f;
        float v = ok ? IV[(size_t)b * T + t] : 0.f;
        for (int c = gg; c < 256; c += 8) {
            float xv = ok ? xin[xoff + (size_t)c * T + t] : 0.f;
            float ln = ok ? ((xv - m) * v * lng[c] + lnb[c]) : 0.f;
            u16 h, l; split_f16(ln, h, l);
            LH[jj * 264 + c] = h; LL[jj * 264 + c] = l;
        }
        int j2 = 64 + (tid >> 8);
        int c2 = tid & 255;
        int t2 = t0 + 62 + (tid >> 8);
        float m2 = MM[(size_t)b * T + t2], v2 = IV[(size_t)b * T + t2];
        float x2 = xin[xoff + (size_t)c2 * T + t2];
        float ln2 = (x2 - m2) * v2 * lng[c2] + lnb[c2];
        u16 h2, l2; split_f16(ln2, h2, l2);
        LH[j2 * 264 + c2] = h2; LL[j2 * 264 + c2] = l2;
    }
    __syncthreads();
    const int lane = tid & 63;
    const int w = tid >> 6;
    const int mg = w & 1, ng = w >> 1;
    const int arow = mg * 32 + (lane & 31);
    const int acol = (lane >> 5) << 3;
    f32x16 acc[4];
#pragma unroll
    for (int n = 0; n < 4; n++)
#pragma unroll
        for (int r = 0; r < 16; r++) acc[n][r] = 0.f;

    for (int k3 = 0; k3 < 3; k3++) {
        for (int kb = 0; kb < 16; kb++) {
            int ao = (arow + k3) * 264 + kb * 16 + acol;
            f16x8 ah = *(const f16x8*)&LH[ao];
            f16x8 al = *(const f16x8*)&LL[ao];
            int kk = k3 * 16 + kb;
#pragma unroll
            for (int n = 0; n < 4; n++) {
                int nt = ng * 4 + n;
                size_t bi = ((size_t)(kk * 16 + nt) * 64 + lane) * 8;
                f16x8 bh = *(const f16x8*)(BH + bi);
                f16x8 bl = *(const f16x8*)(BL + bi);
                acc[n] = __builtin_amdgcn_mfma_f32_32x32x16_f16(ah, bh, acc[n], 0, 0, 0);
                acc[n] = __builtin_amdgcn_mfma_f32_32x32x16_f16(ah, bl, acc[n], 0, 0, 0);
                acc[n] = __builtin_amdgcn_mfma_f32_32x32x16_f16(al, bh, acc[n], 0, 0, 0);
            }
        }
    }
    const float ks = 0.5773502691896258f;
    const int thalf = (lane >> 5) << 2;
    const size_t gbase = ((size_t)b * T + t0 + mg * 32) * 512;
#pragma unroll
    for (int n = 0; n < 4; n++) {
        int oc = (ng * 4 + n) * 32 + (lane & 31);
        float bb = b1[oc];
#pragma unroll
        for (int r = 0; r < 16; r++) {
            int trow = thalf + ((r >> 2) << 3) + (r & 3);
            float y = (acc[n][r] + bb) * ks;
            float ge = 0.5f * y * (1.0f + erff(y * 0.7071067811865476f));
            u16 h, l; split_f16(ge, h, l);
            G_P[gbase + (size_t)trow * 512 + oc] = ((u32)h << 16) | (u32)l;
        }
    }
}

// ---------------- conv2: 1x1 conv(512->256) + residual + stats via MFMA -----
// Block: 512 thr, tile M=64 x N=256, K=512. Wave: mg=w&1, ng=w>>1 (2 n32).
__global__ __launch_bounds__(512, 4) void k_conv2(
    const u32* __restrict__ G_P,
    const float* __restrict__ xin, float* __restrict__ xout,
    const u16* __restrict__ BH, const u16* __restrict__ BL,
    const float* __restrict__ b2, const float* __restrict__ mask,
    float* __restrict__ MM, float* __restrict__ IV, int T) {
    __shared__ float SOUT[64 * 260];
    __shared__ float rs[512], rs2[512];
    const int tid = threadIdx.x;
    const int b = blockIdx.y, t0 = blockIdx.x * 64;
    const int lane = tid & 63;
    const int w = tid >> 6;
    const int mg = w & 1, ng = w >> 1;
    const int acol = (lane >> 5) << 3;
    f32x16 acc[2];
#pragma unroll
    for (int n = 0; n < 2; n++)
#pragma unroll
        for (int r = 0; r < 16; r++) acc[n][r] = 0.f;

    const size_t grow = ((size_t)b * T + t0 + mg * 32 + (lane & 31)) * 512;
    for (int kb = 0; kb < 32; kb++) {
        uint4 p0 = *(const uint4*)(G_P + grow + kb * 16 + acol);
        uint4 p1 = *(const uint4*)(G_P + grow + kb * 16 + acol + 4);
        union { f16x8 v; u32 u[4]; } ah, al;
        ah.u[0] = __builtin_amdgcn_perm(p0.y, p0.x, 0x07060302u);
        al.u[0] = __builtin_amdgcn_perm(p0.y, p0.x, 0x05040100u);
        ah.u[1] = __builtin_amdgcn_perm(p0.w, p0.z, 0x07060302u);
        al.u[1] = __builtin_amdgcn_perm(p0.w, p0.z, 0x05040100u);
        ah.u[2] = __builtin_amdgcn_perm(p1.y, p1.x, 0x07060302u);
        al.u[2] = __builtin_amdgcn_perm(p1.y, p1.x, 0x05040100u);
        ah.u[3] = __builtin_amdgcn_perm(p1.w, p1.z, 0x07060302u);
        al.u[3] = __builtin_amdgcn_perm(p1.w, p1.z, 0x05040100u);
#pragma unroll
        for (int n = 0; n < 2; n++) {
            int nt = ng * 2 + n;
            size_t bi = ((size_t)(kb * 8 + nt) * 64 + lane) * 8;
            f16x8 bh = *(const f16x8*)(BH + bi);
            f16x8 bl = *(const f16x8*)(BL + bi);
            acc[n] = __builtin_amdgcn_mfma_f32_32x32x16_f16(ah.v, bh, acc[n], 0, 0, 0);
            acc[n] = __builtin_amdgcn_mfma_f32_32x32x16_f16(ah.v, bl, acc[n], 0, 0, 0);
            acc[n] = __builtin_amdgcn_mfma_f32_32x32x16_f16(al.v, bh, acc[n], 0, 0, 0);
        }
    }
    const int thalf = (lane >> 5) << 2;
#pragma unroll
    for (int n = 0; n < 2; n++) {
        int oc = (ng * 2 + n) * 32 + (lane & 31);
#pragma unroll
        for (int r = 0; r < 16; r++) {
            int trow = mg * 32 + thalf + ((r >> 2) << 3) + (r & 3);
            SOUT[trow * 260 + oc] = acc[n][r];
        }
    }
    __syncthreads();
    const int tl = tid & 63, gg = tid >> 6;
    const size_t xoff = (size_t)b * 256 * T;
    float mk = mask[(size_t)b * T + t0 + tl];
    float s = 0.f, s2 = 0.f;
    for (int o = 0; o < 32; o++) {
        int c = gg * 32 + o;
        size_t adr = xoff + (size_t)c * T + t0 + tl;
        float val = (xin[adr] + SOUT[tl * 260 + c] + b2[c]) * mk;
        xout[adr] = val;
        s += val; s2 += val * val;
    }
    rs[gg * 64 + tl] = s; rs2[gg * 64 + tl] = s2;
    __syncthreads();
    if (tid < 64) {
        float ss = 0.f, ss2 = 0.f;
#pragma unroll
        for (int k = 0; k < 8; k++) {
            ss += rs[k * 64 + tid]; ss2 += rs2[k * 64 + tid];
        }
        float m = ss * (1.0f / 256.0f);
        float var = ss2 * (1.0f / 256.0f) - m * m;
        MM[(size_t)b * T + t0 + tid] = m;
        IV[(size_t)b * T + t0 + tid] = 1.0f / sqrtf(var + 1e-5f);
    }
}

// ---------------- final LN*mask + causal conv (k=3, 256->256), fp32 ---------
__global__ __launch_bounds__(512, 8) void k_lnconv(
    const float* __restrict__ xin, float* __restrict__ xout,
    const float* __restrict__ MM, const float* __restrict__ IV,
    const float* __restrict__ lg, const float* __restrict__ lb,
    const float* __restrict__ wt, const float* __restrict__ bias,
    const float* __restrict__ mask, int T) {
    __shared__ float CH[128 * 66];
    __shared__ float sm_m[66], sm_v[66], sm_k[66];
    const int b = blockIdx.y, t0 = blockIdx.x * 64;
    const size_t xoff = (size_t)b * 256 * T;
    if (threadIdx.x < 66) {
        int t = t0 - 2 + (int)threadIdx.x;
        sm_m[threadIdx.x] = (t >= 0) ? MM[(size_t)b * T + t] : 0.f;
        sm_v[threadIdx.x] = (t >= 0) ? IV[(size_t)b * T + t] : 0.f;
        sm_k[threadIdx.x] = (t >= 0) ? mask[(size_t)b * T + t] : 0.f;
    }
    const int tl = threadIdx.x & 63;
    const int g = __builtin_amdgcn_readfirstlane((int)(threadIdx.x >> 6));
    float acc[32];
#pragma unroll
    for (int o = 0; o < 32; o++) acc[o] = 0.f;
    const float* wp = wt + g * 32;

    for (int ch = 0; ch < 2; ch++) {
        __syncthreads();
        for (int i = threadIdx.x; i < 128 * 66; i += 512) {
            int c = i / 66, j = i - c * 66;
            int t = t0 - 2 + j;
            int cc = ch * 128 + c;
            float val = 0.f;
            if (t >= 0)
                val = ((xin[xoff + (size_t)cc * T + t] - sm_m[j]) * sm_v[j] *
                           lg[cc] + lb[cc]) * sm_k[j];
            CH[i] = val;
        }
        __syncthreads();
        for (int c = 0; c < 128; ++c) {
#pragma unroll
            for (int k = 0; k < 3; ++k) {
                float xv = CH[c * 66 + tl + k];
                const float* wr = wp + (size_t)((ch * 128 + c) * 3 + k) * 256;
#pragma unroll
                for (int o = 0; o < 32; o++) acc[o] = fmaf(wr[o], xv, acc[o]);
            }
        }
    }
    float mk = mask[(size_t)b * T + t0 + tl];
#pragma unroll
    for (int o = 0; o < 32; o++) {
        int oc = g * 32 + o;
        xout[xoff + (size_t)oc * T + t0 + tl] = (acc[o] + bias[oc]) * mk;
    }
}

// ---------------- group-by-segments (scatter mean) --------------------------
__global__ __launch_bounds__(256) void k_counts(const int* __restrict__ m2p,
                                                int* __restrict__ cnt) {
    __shared__ int c[512];
    int b = blockIdx.x;
    for (int i = threadIdx.x; i < 512; i += 256) c[i] = 0;
    __syncthreads();
    for (int t = threadIdx.x; t < 2048; t += 256) {
        int p = m2p[b * 2048 + t];
        if (p >= 1 && p <= 512) atomicAdd(&c[p - 1], 1);
    }
    __syncthreads();
    for (int i = threadIdx.x; i < 512; i += 256) cnt[b * 512 + i] = c[i];
}

__global__ __launch_bounds__(256) void k_scatter(const float* __restrict__ h,
                                                 const int* __restrict__ m2p,
                                                 float* __restrict__ g) {
    extern __shared__ float sm[];
    float* HT = sm;
    int* ph = (int*)(sm + 256 * 65);
    int b = blockIdx.y, t0 = blockIdx.x * 64;
    if (threadIdx.x < 64) ph[threadIdx.x] = m2p[b * 2048 + t0 + threadIdx.x];
    for (int i = threadIdx.x; i < 256 * 64; i += 256) {
        int c = i >> 6, j = i & 63;
        HT[c * 65 + j] = h[((size_t)b * 256 + c) * 2048 + t0 + j];
    }
    __syncthreads();
    int c = threadIdx.x;
    float run = 0.f;
    int cur = ph[0];
    for (int j = 0; j < 64; j++) {
        int p = ph[j];
        if (p != cur) {
            if (cur >= 1 && cur <= 512)
                atomicAdd(&g[((size_t)b * 256 + c) * 512 + cur - 1], run);
            run = 0.f;
            cur = p;
        }
        run += HT[c * 65 + j];
    }
    if (cur >= 1 && cur <= 512)
        atomicAdd(&g[((size_t)b * 256 + c) * 512 + cur - 1], run);
}

__global__ __launch_bounds__(512) void k_postprep(float* __restrict__ g,
                                                  const int* __restrict__ cnt,
                                                  float* __restrict__ MM,
                                                  float* __restrict__ IV) {
    int b = blockIdx.x, l = threadIdx.x;
    int c1 = cnt[b * 512 + l];
    if (c1 < 1) c1 = 1;
    float rc = 1.0f / (float)c1;
    float s = 0.f, s2 = 0.f;
    for (int c = 0; c < 256; c++) {
        size_t idx = ((size_t)b * 256 + c) * 512 + l;
        float v = g[idx] * rc;
        g[idx] = v;
        s += v; s2 += v * v;
    }
    float m = s * (1.0f / 256.0f);
    float var = s2 * (1.0f / 256.0f) - m * m;
    MM[(size_t)b * 512 + l] = m;
    IV[(size_t)b * 512 + l] = 1.0f / sqrtf(var + 1e-5f);
}

// ---------------- VQ --------------------------------------------------------
__global__ __launch_bounds__(256) void k_vq(const float* __restrict__ z,
                                            const float* __restrict__ cb,
                                            int* __restrict__ idxout,
                                            float* __restrict__ out,
                                            float* __restrict__ lossacc) {
    int n = blockIdx.x * 256 + threadIdx.x;
    int b = n >> 9, l = n & 511;
    float zr[64];
#pragma unroll
    for (int c = 0; c < 64; c++) zr[c] = z[((size_t)b * 64 + c) * 512 + l];
    float best = 3.4e38f;
    int bi = 0;
    for (int k = 0; k < 128; k++) {
        const float* cr = cb + k * 64;
        float d = 0.f;
#pragma unroll
        for (int c = 0; c < 64; c++) {
            float t = zr[c] - cr[c];
            d = fmaf(t, t, d);
        }
        if (d < best) { best = d; bi = k; }
    }
    idxout[n] = bi;
    out[OUT_IDX_OFF + n] = (float)bi;
    atomicAdd(lossacc, best);
}

__global__ void k_loss(const float* __restrict__ acc, float* __restrict__ out) {
    if (threadIdx.x == 0 && blockIdx.x == 0)
        out[OUT_LOSS_OFF] = 0.25f * acc[0] * (1.0f / 524288.0f);
}

// ---------------- proj_out --------------------------------------------------
__global__ __launch_bounds__(256) void k_projout(const float* __restrict__ cb,
                                                 const int* __restrict__ idx,
                                                 const float* __restrict__ wt,
                                                 const float* __restrict__ bias,
                                                 float* __restrict__ out) {
    __shared__ float Q[64 * 64];
    __shared__ int ids[64];
    int b = blockIdx.y, l0 = blockIdx.x * 64;
    if (threadIdx.x < 64) ids[threadIdx.x] = idx[b * 512 + l0 + threadIdx.x];
    __syncthreads();
    for (int i = threadIdx.x; i < 4096; i += 256) {
        int c = i >> 6, l = i & 63;
        Q[c * 64 + l] = cb[ids[l] * 64 + c];
    }
    __syncthreads();
    int tl = threadIdx.x & 63;
    int g = __builtin_amdgcn_readfirstlane((int)(threadIdx.x >> 6));
    float acc[64];
#pragma unroll
    for (int o = 0; o < 64; o++) acc[o] = 0.f;
    for (int i = 0; i < 64; i++) {
        float xv = Q[i * 64 + tl];
        const float* wr = wt + i * 256 + g * 64;
#pragma unroll
        for (int o = 0; o < 64; o++) acc[o] = fmaf(wr[o], xv, acc[o]);
    }
#pragma unroll
    for (int o = 0; o < 64; o++) {
        int oc = g * 64 + o;
        out[(size_t)b * 131072 + (size_t)oc * 512 + l0 + tl] = acc[o] + bias[oc];
    }
}

// ---------------------------------------------------------------------------
extern "C" void kernel_launch(void* const* d_in, const int* in_sizes, int n_in,
                              void* d_out, int out_size, void* d_ws, size_t ws_size,
                              hipStream_t stream) {
    (void)in_sizes; (void)n_in; (void)out_size; (void)ws_size;
    const float* x          = (const float*)d_in[0];
    const float* in_np      = (const float*)d_in[1];
    const int*   mel2ph     = (const int*)d_in[2];
    const float* ph_np      = (const float*)d_in[3];
    const float* conv_in_w  = (const float*)d_in[4];
    const float* conv_in_b  = (const float*)d_in[5];
    const float* e_ln_g = (const float*)d_in[6];
    const float* e_ln_b = (const float*)d_in[7];
    const float* e_w1   = (const float*)d_in[8];
    const float* e_b1   = (const float*)d_in[9];
    const float* e_w2   = (const float*)d_in[10];
    const float* e_b2   = (const float*)d_in[11];
    const float* e_lg   = (const float*)d_in[12];
    const float* e_lb   = (const float*)d_in[13];
    const float* e_pw   = (const float*)d_in[14];
    const float* e_pb   = (const float*)d_in[15];
    const float* p_ln_g = (const float*)d_in[16];
    const float* p_ln_b = (const float*)d_in[17];
    const float* p_w1   = (const float*)d_in[18];
    const float* p_b1   = (const float*)d_in[19];
    const float* p_w2   = (const float*)d_in[20];
    const float* p_b2   = (const float*)d_in[21];
    const float* p_lg   = (const float*)d_in[22];
    const float* p_lb   = (const float*)d_in[23];
    const float* p_pw   = (const float*)d_in[24];
    const float* p_pb   = (const float*)d_in[25];
    const float* proj_in_w  = (const float*)d_in[26];
    const float* proj_in_b  = (const float*)d_in[27];
    const float* proj_out_w = (const float*)d_in[28];
    const float* proj_out_b = (const float*)d_in[29];
    const float* codebook   = (const float*)d_in[30];
    float* out = (float*)d_out;

    float* ws = (float*)d_ws;
    float* A      = ws;                        // 8388608
    float* Bb     = A + 8388608;               // 8388608
    float* CINT   = Bb + 8388608;              // 20480
    float* PSTT_E = CINT + 20480;              // 196608
    float* PSTT_P = PSTT_E + 196608;           // 196608
    float* PINT   = PSTT_P + 196608;           // 16384
    float* POUTT  = PINT + 16384;              // 16384
    float* Z      = POUTT + 16384;             // 524288
    float* MM     = Z + 524288;                // 32768
    float* IV     = MM + 32768;                // 32768
    int*   CNT    = (int*)(IV + 32768);        // 8192
    int*   IDX    = CNT + 8192;                // 8192
    float* LOSS   = (float*)(IDX + 8192);      // 64 (aligned pad)
    u16*   BH1E   = (u16*)(LOSS + 64);         // 3932160 each
    u16*   BL1E   = BH1E + 3932160;
    u16*   BH1P   = BL1E + 3932160;
    u16*   BL1P   = BH1P + 3932160;
    u16*   BH2E   = BL1P + 3932160;            // 1310720 each
    u16*   BL2E   = BH2E + 1310720;
    u16*   BH2P   = BL2E + 1310720;
    u16*   BL2P   = BH2P + 1310720;
    u32*   G_P    = (u32*)(BL2P + 1310720);    // 16777216

    // weight prep (ws re-poisoned every call -> recompute)
    k_t_w1mf<<<dim3(4096), dim3(256), 0, stream>>>(e_w1, BH1E, BL1E, 10);
    k_t_w1mf<<<dim3(4096), dim3(256), 0, stream>>>(p_w1, BH1P, BL1P, 10);
    k_t_w2mf<<<dim3(2048), dim3(256), 0, stream>>>(e_w2, BH2E, BL2E, 10);
    k_t_w2mf<<<dim3(2048), dim3(256), 0, stream>>>(p_w2, BH2P, BL2P, 10);
    k_t_mat  <<<dim3(80),  dim3(256), 0, stream>>>(conv_in_w, CINT, 1, 256, 80);
    k_t_conv3<<<dim3(768), dim3(256), 0, stream>>>(e_pw, PSTT_E, 1, 256, 256);
    k_t_conv3<<<dim3(768), dim3(256), 0, stream>>>(p_pw, PSTT_P, 1, 256, 256);
    k_t_mat  <<<dim3(64),  dim3(256), 0, stream>>>(proj_in_w, PINT, 1, 64, 256);
    k_t_mat  <<<dim3(64),  dim3(256), 0, stream>>>(proj_out_w, POUTT, 1, 256, 64);

    const size_t sm_scat = 256 * 65 * sizeof(float) + 64 * sizeof(int);

    // ---- conv_in + mask -> A (+ LN stats for encoder layer 0)
    k_pw<80, 256, 64, true><<<dim3(32, 16), dim3(256), 80 * 64 * 4, stream>>>(
        x, CINT, conv_in_b, in_np, A, MM, IV, 2048);

    // ---- encoder: 10 sub-blocks, ping-pong A<->B (ends in A)
    float* cur = A;
    float* nxt = Bb;
    for (int s = 0; s < 10; s++) {
        k_conv1<<<dim3(32, 16), dim3(512), 0, stream>>>(
            cur, G_P, MM, IV, e_ln_g + s * 256, e_ln_b + s * 256,
            BH1E + (size_t)s * 393216, BL1E + (size_t)s * 393216,
            e_b1 + s * 512, 2048);
        k_conv2<<<dim3(32, 16), dim3(512), 0, stream>>>(
            G_P, cur, nxt, BH2E + (size_t)s * 131072, BL2E + (size_t)s * 131072,
            e_b2 + s * 256, in_np, MM, IV, 2048);
        float* t = cur; cur = nxt; nxt = t;
    }
    k_lnconv<<<dim3(32, 16), dim3(512), 0, stream>>>(
        cur, nxt, MM, IV, e_lg, e_lb, PSTT_E, e_pb, in_np, 2048);

    // ---- group-by-segs: B (T=2048) -> A (compact [16,256,512])
    hipMemsetAsync(A, 0, (size_t)2097152 * 4, stream);
    hipMemsetAsync(LOSS, 0, 4, stream);
    k_counts<<<dim3(16), dim3(256), 0, stream>>>(mel2ph, CNT);
    k_scatter<<<dim3(32, 16), dim3(256), sm_scat, stream>>>(Bb, mel2ph, A);
    k_postprep<<<dim3(16), dim3(512), 0, stream>>>(A, CNT, MM, IV);

    // ---- postnet: 10 sub-blocks on T=512, ping-pong (ends in A)
    cur = A; nxt = Bb;
    for (int s = 0; s < 10; s++) {
        k_conv1<<<dim3(8, 16), dim3(512), 0, stream>>>(
            cur, G_P, MM, IV, p_ln_g + s * 256, p_ln_b + s * 256,
            BH1P + (size_t)s * 393216, BL1P + (size_t)s * 393216,
            p_b1 + s * 512, 512);
        k_conv2<<<dim3(8, 16), dim3(512), 0, stream>>>(
            G_P, cur, nxt, BH2P + (size_t)s * 131072, BL2P + (size_t)s * 131072,
            p_b2 + s * 256, ph_np, MM, IV, 512);
        float* t = cur; cur = nxt; nxt = t;
    }
    k_lnconv<<<dim3(8, 16), dim3(512), 0, stream>>>(
        cur, nxt, MM, IV, p_lg, p_lb, PSTT_P, p_pb, ph_np, 512);

    // ---- proj_in: B -> Z [16,64,512]
    k_pw<256, 64, 16, false><<<dim3(8, 16), dim3(256), 256 * 64 * 4, stream>>>(
        Bb, PINT, proj_in_b, nullptr, Z, nullptr, nullptr, 512);

    // ---- VQ + loss + proj_out
    k_vq<<<dim3(32), dim3(256), 0, stream>>>(Z, codebook, IDX, out, LOSS);
    k_loss<<<dim3(1), dim3(64), 0, stream>>>(LOSS, out);
    k_projout<<<dim3(8, 16), dim3(256), 0, stream>>>(codebook, IDX, POUTT,
                                                     proj_out_b, out);
}

// Round 8
// 3999.003 us; speedup vs baseline: 2.7162x; 1.8339x over previous
//
#include <hip/hip_runtime.h>
#include <hip/hip_bf16.h>

// ---------------------------------------------------------------------------
// StyleEncoder pipeline for MI355X (gfx950).  R8: fused sub-block kernel
// (LN -> conv1 K=768 -> GELU -> conv2 K=512 -> residual) with the GELU
// intermediate held in LDS (no G_P HBM round trip). Split-f16 MFMA
// (x=hi+lo, w=hi+lo, 3x mfma_f32_32x32x16_f16, ~2^-23 rel err/GEMM).
// All inputs fp32; d_out fp32: out @0, vq_loss @2097152, idx @2097153.
// ---------------------------------------------------------------------------

typedef unsigned short u16;
typedef unsigned int u32;
typedef __attribute__((ext_vector_type(8))) _Float16 f16x8;
typedef __attribute__((ext_vector_type(16))) float f32x16;

#define OUT_LOSS_OFF 2097152
#define OUT_IDX_OFF  2097153

__device__ __forceinline__ void split_f16(float x, u16& h, u16& l) {
    union { _Float16 f; u16 u; } a, b;
    a.f = (_Float16)x;              // RNE f32->f16
    float hf = (float)a.f;
    b.f = (_Float16)(x - hf);       // residual, RNE to f16
    h = a.u; l = b.u;
}

// ---------------- weight transposes (fp32 kept for lnconv/pw) ---------------
__global__ __launch_bounds__(256) void k_t_conv3(const float* __restrict__ w,
                                                 float* __restrict__ wt,
                                                 int G, int O, int Cin) {
    size_t n = (size_t)G * O * Cin * 3;
    for (size_t i = (size_t)blockIdx.x * 256 + threadIdx.x; i < n;
         i += (size_t)gridDim.x * 256) {
        int k = (int)(i % 3);
        size_t r = i / 3;
        int c = (int)(r % Cin); r /= Cin;
        int o = (int)(r % O);
        int g = (int)(r / O);
        wt[((size_t)g * Cin * 3 + (size_t)(c * 3 + k)) * O + o] = w[i];
    }
}

__global__ __launch_bounds__(256) void k_t_mat(const float* __restrict__ w,
                                               float* __restrict__ wt,
                                               int G, int O, int I) {
    size_t n = (size_t)G * O * I;
    for (size_t i = (size_t)blockIdx.x * 256 + threadIdx.x; i < n;
         i += (size_t)gridDim.x * 256) {
        int ci = (int)(i % I);
        int o  = (int)((i / I) % O);
        int g  = (int)(i / ((size_t)I * O));
        wt[((size_t)g * I + ci) * O + o] = w[i];
    }
}

// ---- W1 -> B-fragment layout, split hi/lo f16.
// idx = ((((s*3+k3)*16+kb)*16+nt)*64+L)*8+j ; val = w1[s][oc][c][k3]
// oc = nt*32+(L&31), c = kb*16+((L>>5)<<3)+j
__global__ __launch_bounds__(256) void k_t_w1mf(const float* __restrict__ w,
                                                u16* __restrict__ BH,
                                                u16* __restrict__ BL, int S) {
    size_t N = (size_t)S * 3 * 16 * 16 * 64 * 8;
    for (size_t i = (size_t)blockIdx.x * 256 + threadIdx.x; i < N;
         i += (size_t)gridDim.x * 256) {
        int j = (int)(i & 7); size_t r = i >> 3;
        int L = (int)(r & 63); r >>= 6;
        int nt = (int)(r & 15); r >>= 4;
        int kb = (int)(r & 15); r >>= 4;
        int k3 = (int)(r % 3); int s = (int)(r / 3);
        int oc = nt * 32 + (L & 31);
        int c = kb * 16 + ((L >> 5) << 3) + j;
        float v = w[(((size_t)s * 512 + oc) * 256 + c) * 3 + k3];
        u16 h, l; split_f16(v, h, l);
        BH[i] = h; BL[i] = l;
    }
}

// ---- W2 -> B-fragment layout. idx = (((s*32+kb)*8+nt)*64+L)*8+j
// val = w2[s][oc][ic], oc = nt*32+(L&31), ic = kb*16+((L>>5)<<3)+j
__global__ __launch_bounds__(256) void k_t_w2mf(const float* __restrict__ w,
                                                u16* __restrict__ BH,
                                                u16* __restrict__ BL, int S) {
    size_t N = (size_t)S * 32 * 8 * 64 * 8;
    for (size_t i = (size_t)blockIdx.x * 256 + threadIdx.x; i < N;
         i += (size_t)gridDim.x * 256) {
        int j = (int)(i & 7);
        int L = (int)((i >> 3) & 63);
        int nt = (int)((i >> 9) & 7);
        int kb = (int)((i >> 12) & 31);
        int s = (int)(i >> 17);
        int oc = nt * 32 + (L & 31);
        int ic = kb * 16 + ((L >> 5) << 3) + j;
        float v = w[((size_t)s * 256 + oc) * 512 + ic];
        u16 h, l; split_f16(v, h, l);
        BH[i] = h; BL[i] = l;
    }
}

// ---------------- pointwise conv (+ optional column stats) ------------------
template <int CIN, int COUT, int CHUNK, bool STATS>
__global__ __launch_bounds__(256) void k_pw(const float* __restrict__ x,
                                            const float* __restrict__ wt,
                                            const float* __restrict__ bias,
                                            const float* __restrict__ mask,
                                            float* __restrict__ y,
                                            float* __restrict__ MM,
                                            float* __restrict__ IV, int T) {
    extern __shared__ float X[];
    constexpr int NG = COUT / CHUNK;
    __shared__ float rs[64 * NG], rs2[64 * NG];
    const int b = blockIdx.y, t0 = blockIdx.x * 64;
    for (int i = threadIdx.x; i < CIN * 64; i += 256) {
        int ci = i >> 6, j = i & 63;
        X[i] = x[((size_t)b * CIN + ci) * T + t0 + j];
    }
    __syncthreads();
    const int tl = threadIdx.x & 63;
    const int g = __builtin_amdgcn_readfirstlane((int)(threadIdx.x >> 6));
    float acc[CHUNK];
#pragma unroll
    for (int o = 0; o < CHUNK; o++) acc[o] = 0.f;
    for (int i = 0; i < CIN; i++) {
        float xv = X[i * 64 + tl];
        const float* wr = wt + (size_t)i * COUT + g * CHUNK;
#pragma unroll
        for (int o = 0; o < CHUNK; o++) acc[o] = fmaf(wr[o], xv, acc[o]);
    }
    float mk = mask ? mask[(size_t)b * T + t0 + tl] : 1.0f;
    float s = 0.f, s2 = 0.f;
#pragma unroll
    for (int o = 0; o < CHUNK; o++) {
        int oc = g * CHUNK + o;
        float val = (acc[o] + bias[oc]) * mk;
        y[((size_t)b * COUT + oc) * T + t0 + tl] = val;
        s += val; s2 += val * val;
    }
    if constexpr (STATS) {
        rs[g * 64 + tl] = s; rs2[g * 64 + tl] = s2;
        __syncthreads();
        if (threadIdx.x < 64) {
            float ss = 0.f, ss2 = 0.f;
#pragma unroll
            for (int gg = 0; gg < NG; gg++) {
                ss += rs[gg * 64 + threadIdx.x];
                ss2 += rs2[gg * 64 + threadIdx.x];
            }
            float m = ss * (1.0f / COUT);
            float var = ss2 * (1.0f / COUT) - m * m;
            MM[(size_t)b * T + t0 + threadIdx.x] = m;
            IV[(size_t)b * T + t0 + threadIdx.x] = 1.0f / sqrtf(var + 1e-5f);
        }
    }
}

// ---------------- fused sub-block: LN->conv1->GELU->conv2->residual ---------
// Tile M=64 t. LDS: LH/LL f16-split LN'd x (66x264); G = packed gelu
// intermediate (64x260 u32), half (256 oc) at a time; SOUT overlays LH/LL.
// MM/IV ping-pong (in != out: halo race across blocks otherwise).
__global__ __launch_bounds__(512, 2) void k_sub(
    const float* __restrict__ xin, float* __restrict__ xout,
    const float* __restrict__ MMi, const float* __restrict__ IVi,
    const float* __restrict__ lng, const float* __restrict__ lnb,
    const u16* __restrict__ B1H, const u16* __restrict__ B1L,
    const float* __restrict__ b1,
    const u16* __restrict__ B2H, const u16* __restrict__ B2L,
    const float* __restrict__ b2, const float* __restrict__ mask,
    float* __restrict__ MMo, float* __restrict__ IVo, int T) {
    __shared__ __align__(16) char smem[140352];
    u16* LH = (u16*)smem;                     // 66*264 u16 = 34848 B
    u16* LL = (u16*)(smem + 34848);           // 34848 B
    u32* G  = (u32*)(smem + 69696);           // 64*260 u32 = 66560 B
    float* SOUT = (float*)smem;               // overlay (64*260 f32 <= 69696)
    float* rs  = (float*)(smem + 136256);     // 512 f32
    float* rs2 = (float*)(smem + 138304);     // 512 f32

    const int tid = threadIdx.x;
    const int b = blockIdx.y, t0 = blockIdx.x * 64;
    const size_t xoff = (size_t)b * 256 * T;

    // ---- stage: LN'd x, split hi/lo f16, layout [j 0..65][c 0..255]
    {
        int jj = tid & 63;
        int gg = tid >> 6;
        int t = t0 - 2 + jj;
        bool ok = (t >= 0);
        float m = ok ? MMi[(size_t)b * T + t] : 0.f;
        float v = ok ? IVi[(size_t)b * T + t] : 0.f;
        for (int c = gg; c < 256; c += 8) {
            float xv = ok ? xin[xoff + (size_t)c * T + t] : 0.f;
            float ln = ok ? ((xv - m) * v * lng[c] + lnb[c]) : 0.f;
            u16 h, l; split_f16(ln, h, l);
            LH[jj * 264 + c] = h; LL[jj * 264 + c] = l;
        }
        int j2 = 64 + (tid >> 8);
        int c2 = tid & 255;
        int t2 = t0 + 62 + (tid >> 8);
        float m2 = MMi[(size_t)b * T + t2], v2 = IVi[(size_t)b * T + t2];
        float x2 = xin[xoff + (size_t)c2 * T + t2];
        float ln2 = (x2 - m2) * v2 * lng[c2] + lnb[c2];
        u16 h2, l2; split_f16(ln2, h2, l2);
        LH[j2 * 264 + c2] = h2; LL[j2 * 264 + c2] = l2;
    }
    __syncthreads();

    const int lane = tid & 63;
    const int w = tid >> 6;
    const int mg = w & 1, ng = w >> 1;        // ng 0..3
    const int arow = mg * 32 + (lane & 31);
    const int acol = (lane >> 5) << 3;
    const int thalf = (lane >> 5) << 2;
    const float ks = 0.5773502691896258f;

    f32x16 acc2[2];
#pragma unroll
    for (int n = 0; n < 2; n++)
#pragma unroll
        for (int r = 0; r < 16; r++) acc2[n][r] = 0.f;

    for (int p = 0; p < 2; p++) {
        // ---- conv1 half p: oc global = p*256 + (ng*2+n)*32 + (lane&31)
        f32x16 acc1[2];
#pragma unroll
        for (int n = 0; n < 2; n++)
#pragma unroll
            for (int r = 0; r < 16; r++) acc1[n][r] = 0.f;
        for (int k3 = 0; k3 < 3; k3++) {
            for (int kb = 0; kb < 16; kb++) {
                int ao = (arow + k3) * 264 + kb * 16 + acol;
                f16x8 ah = *(const f16x8*)&LH[ao];
                f16x8 al = *(const f16x8*)&LL[ao];
                int kk = k3 * 16 + kb;
#pragma unroll
                for (int n = 0; n < 2; n++) {
                    int nt = p * 8 + ng * 2 + n;
                    size_t bi = ((size_t)(kk * 16 + nt) * 64 + lane) * 8;
                    f16x8 bh = *(const f16x8*)(B1H + bi);
                    f16x8 bl = *(const f16x8*)(B1L + bi);
                    acc1[n] = __builtin_amdgcn_mfma_f32_32x32x16_f16(ah, bh, acc1[n], 0, 0, 0);
                    acc1[n] = __builtin_amdgcn_mfma_f32_32x32x16_f16(ah, bl, acc1[n], 0, 0, 0);
                    acc1[n] = __builtin_amdgcn_mfma_f32_32x32x16_f16(al, bh, acc1[n], 0, 0, 0);
                }
            }
        }
        __syncthreads();  // prior G fully consumed (and stage done for p=0)
        // ---- gelu + pack -> G[t][oc_local], row stride 260
#pragma unroll
        for (int n = 0; n < 2; n++) {
            int oc_l = (ng * 2 + n) * 32 + (lane & 31);
            float bb = b1[p * 256 + oc_l];
#pragma unroll
            for (int r = 0; r < 16; r++) {
                int trow = mg * 32 + thalf + ((r >> 2) << 3) + (r & 3);
                float y = (acc1[n][r] + bb) * ks;
                float ge = 0.5f * y * (1.0f + erff(y * 0.7071067811865476f));
                u16 h, l; split_f16(ge, h, l);
                G[trow * 260 + oc_l] = ((u32)h << 16) | (u32)l;
            }
        }
        __syncthreads();
        // ---- conv2 partial: K chunk = oc_local 0..255 of half p
        const int grow = (mg * 32 + (lane & 31)) * 260;
        for (int kb = 0; kb < 16; kb++) {
            const u32* gp = &G[grow + kb * 16 + acol];
            uint4 p0 = *(const uint4*)gp;
            uint4 p1 = *(const uint4*)(gp + 4);
            union { f16x8 v; u32 u[4]; } ah, al;
            ah.u[0] = __builtin_amdgcn_perm(p0.y, p0.x, 0x07060302u);
            al.u[0] = __builtin_amdgcn_perm(p0.y, p0.x, 0x05040100u);
            ah.u[1] = __builtin_amdgcn_perm(p0.w, p0.z, 0x07060302u);
            al.u[1] = __builtin_amdgcn_perm(p0.w, p0.z, 0x05040100u);
            ah.u[2] = __builtin_amdgcn_perm(p1.y, p1.x, 0x07060302u);
            al.u[2] = __builtin_amdgcn_perm(p1.y, p1.x, 0x05040100u);
            ah.u[3] = __builtin_amdgcn_perm(p1.w, p1.z, 0x07060302u);
            al.u[3] = __builtin_amdgcn_perm(p1.w, p1.z, 0x05040100u);
            int kbg = p * 16 + kb;
#pragma unroll
            for (int n = 0; n < 2; n++) {
                int nt = ng * 2 + n;
                size_t bi = ((size_t)(kbg * 8 + nt) * 64 + lane) * 8;
                f16x8 bh = *(const f16x8*)(B2H + bi);
                f16x8 bl = *(const f16x8*)(B2L + bi);
                acc2[n] = __builtin_amdgcn_mfma_f32_32x32x16_f16(ah.v, bh, acc2[n], 0, 0, 0);
                acc2[n] = __builtin_amdgcn_mfma_f32_32x32x16_f16(ah.v, bl, acc2[n], 0, 0, 0);
                acc2[n] = __builtin_amdgcn_mfma_f32_32x32x16_f16(al.v, bh, acc2[n], 0, 0, 0);
            }
        }
        __syncthreads();  // G consumed; (p=1: LH/LL reads also done -> SOUT ok)
    }
    // ---- epilogue: transpose acc2 via SOUT (overlays LH/LL)
#pragma unroll
    for (int n = 0; n < 2; n++) {
        int oc = (ng * 2 + n) * 32 + (lane & 31);
#pragma unroll
        for (int r = 0; r < 16; r++) {
            int trow = mg * 32 + thalf + ((r >> 2) << 3) + (r & 3);
            SOUT[trow * 260 + oc] = acc2[n][r];
        }
    }
    __syncthreads();
    const int tl = tid & 63, gg = tid >> 6;
    float mk = mask[(size_t)b * T + t0 + tl];
    float s = 0.f, s2 = 0.f;
    for (int o = 0; o < 32; o++) {
        int c = gg * 32 + o;
        size_t adr = xoff + (size_t)c * T + t0 + tl;
        float val = (xin[adr] + SOUT[tl * 260 + c] + b2[c]) * mk;
        xout[adr] = val;
        s += val; s2 += val * val;
    }
    rs[gg * 64 + tl] = s; rs2[gg * 64 + tl] = s2;
    __syncthreads();
    if (tid < 64) {
        float ss = 0.f, ss2 = 0.f;
#pragma unroll
        for (int k = 0; k < 8; k++) {
            ss += rs[k * 64 + tid]; ss2 += rs2[k * 64 + tid];
        }
        float m = ss * (1.0f / 256.0f);
        float var = ss2 * (1.0f / 256.0f) - m * m;
        MMo[(size_t)b * T + t0 + tid] = m;
        IVo[(size_t)b * T + t0 + tid] = 1.0f / sqrtf(var + 1e-5f);
    }
}

// ---------------- final LN*mask + causal conv (k=3, 256->256), fp32 ---------
__global__ __launch_bounds__(512, 8) void k_lnconv(
    const float* __restrict__ xin, float* __restrict__ xout,
    const float* __restrict__ MM, const float* __restrict__ IV,
    const float* __restrict__ lg, const float* __restrict__ lb,
    const float* __restrict__ wt, const float* __restrict__ bias,
    const float* __restrict__ mask, int T) {
    __shared__ float CH[128 * 66];
    __shared__ float sm_m[66], sm_v[66], sm_k[66];
    const int b = blockIdx.y, t0 = blockIdx.x * 64;
    const size_t xoff = (size_t)b * 256 * T;
    if (threadIdx.x < 66) {
        int t = t0 - 2 + (int)threadIdx.x;
        sm_m[threadIdx.x] = (t >= 0) ? MM[(size_t)b * T + t] : 0.f;
        sm_v[threadIdx.x] = (t >= 0) ? IV[(size_t)b * T + t] : 0.f;
        sm_k[threadIdx.x] = (t >= 0) ? mask[(size_t)b * T + t] : 0.f;
    }
    const int tl = threadIdx.x & 63;
    const int g = __builtin_amdgcn_readfirstlane((int)(threadIdx.x >> 6));
    float acc[32];
#pragma unroll
    for (int o = 0; o < 32; o++) acc[o] = 0.f;
    const float* wp = wt + g * 32;

    for (int ch = 0; ch < 2; ch++) {
        __syncthreads();
        for (int i = threadIdx.x; i < 128 * 66; i += 512) {
            int c = i / 66, j = i - c * 66;
            int t = t0 - 2 + j;
            int cc = ch * 128 + c;
            float val = 0.f;
            if (t >= 0)
                val = ((xin[xoff + (size_t)cc * T + t] - sm_m[j]) * sm_v[j] *
                           lg[cc] + lb[cc]) * sm_k[j];
            CH[i] = val;
        }
        __syncthreads();
        for (int c = 0; c < 128; ++c) {
#pragma unroll
            for (int k = 0; k < 3; ++k) {
                float xv = CH[c * 66 + tl + k];
                const float* wr = wp + (size_t)((ch * 128 + c) * 3 + k) * 256;
#pragma unroll
                for (int o = 0; o < 32; o++) acc[o] = fmaf(wr[o], xv, acc[o]);
            }
        }
    }
    float mk = mask[(size_t)b * T + t0 + tl];
#pragma unroll
    for (int o = 0; o < 32; o++) {
        int oc = g * 32 + o;
        xout[xoff + (size_t)oc * T + t0 + tl] = (acc[o] + bias[oc]) * mk;
    }
}

// ---------------- group-by-segments (scatter mean) --------------------------
__global__ __launch_bounds__(256) void k_counts(const int* __restrict__ m2p,
                                                int* __restrict__ cnt) {
    __shared__ int c[512];
    int b = blockIdx.x;
    for (int i = threadIdx.x; i < 512; i += 256) c[i] = 0;
    __syncthreads();
    for (int t = threadIdx.x; t < 2048; t += 256) {
        int p = m2p[b * 2048 + t];
        if (p >= 1 && p <= 512) atomicAdd(&c[p - 1], 1);
    }
    __syncthreads();
    for (int i = threadIdx.x; i < 512; i += 256) cnt[b * 512 + i] = c[i];
}

__global__ __launch_bounds__(256) void k_scatter(const float* __restrict__ h,
                                                 const int* __restrict__ m2p,
                                                 float* __restrict__ g) {
    extern __shared__ float sm[];
    float* HT = sm;
    int* ph = (int*)(sm + 256 * 65);
    int b = blockIdx.y, t0 = blockIdx.x * 64;
    if (threadIdx.x < 64) ph[threadIdx.x] = m2p[b * 2048 + t0 + threadIdx.x];
    for (int i = threadIdx.x; i < 256 * 64; i += 256) {
        int c = i >> 6, j = i & 63;
        HT[c * 65 + j] = h[((size_t)b * 256 + c) * 2048 + t0 + j];
    }
    __syncthreads();
    int c = threadIdx.x;
    float run = 0.f;
    int cur = ph[0];
    for (int j = 0; j < 64; j++) {
        int p = ph[j];
        if (p != cur) {
            if (cur >= 1 && cur <= 512)
                atomicAdd(&g[((size_t)b * 256 + c) * 512 + cur - 1], run);
            run = 0.f;
            cur = p;
        }
        run += HT[c * 65 + j];
    }
    if (cur >= 1 && cur <= 512)
        atomicAdd(&g[((size_t)b * 256 + c) * 512 + cur - 1], run);
}

__global__ __launch_bounds__(512) void k_postprep(float* __restrict__ g,
                                                  const int* __restrict__ cnt,
                                                  float* __restrict__ MM,
                                                  float* __restrict__ IV) {
    int b = blockIdx.x, l = threadIdx.x;
    int c1 = cnt[b * 512 + l];
    if (c1 < 1) c1 = 1;
    float rc = 1.0f / (float)c1;
    float s = 0.f, s2 = 0.f;
    for (int c = 0; c < 256; c++) {
        size_t idx = ((size_t)b * 256 + c) * 512 + l;
        float v = g[idx] * rc;
        g[idx] = v;
        s += v; s2 += v * v;
    }
    float m = s * (1.0f / 256.0f);
    float var = s2 * (1.0f / 256.0f) - m * m;
    MM[(size_t)b * 512 + l] = m;
    IV[(size_t)b * 512 + l] = 1.0f / sqrtf(var + 1e-5f);
}

// ---------------- VQ --------------------------------------------------------
__global__ __launch_bounds__(256) void k_vq(const float* __restrict__ z,
                                            const float* __restrict__ cb,
                                            int* __restrict__ idxout,
                                            float* __restrict__ out,
                                            float* __restrict__ lossacc) {
    int n = blockIdx.x * 256 + threadIdx.x;
    int b = n >> 9, l = n & 511;
    float zr[64];
#pragma unroll
    for (int c = 0; c < 64; c++) zr[c] = z[((size_t)b * 64 + c) * 512 + l];
    float best = 3.4e38f;
    int bi = 0;
    for (int k = 0; k < 128; k++) {
        const float* cr = cb + k * 64;
        float d = 0.f;
#pragma unroll
        for (int c = 0; c < 64; c++) {
            float t = zr[c] - cr[c];
            d = fmaf(t, t, d);
        }
        if (d < best) { best = d; bi = k; }
    }
    idxout[n] = bi;
    out[OUT_IDX_OFF + n] = (float)bi;
    atomicAdd(lossacc, best);
}

__global__ void k_loss(const float* __restrict__ acc, float* __restrict__ out) {
    if (threadIdx.x == 0 && blockIdx.x == 0)
        out[OUT_LOSS_OFF] = 0.25f * acc[0] * (1.0f / 524288.0f);
}

// ---------------- proj_out --------------------------------------------------
__global__ __launch_bounds__(256) void k_projout(const float* __restrict__ cb,
                                                 const int* __restrict__ idx,
                                                 const float* __restrict__ wt,
                                                 const float* __restrict__ bias,
                                                 float* __restrict__ out) {
    __shared__ float Q[64 * 64];
    __shared__ int ids[64];
    int b = blockIdx.y, l0 = blockIdx.x * 64;
    if (threadIdx.x < 64) ids[threadIdx.x] = idx[b * 512 + l0 + threadIdx.x];
    __syncthreads();
    for (int i = threadIdx.x; i < 4096; i += 256) {
        int c = i >> 6, l = i & 63;
        Q[c * 64 + l] = cb[ids[l] * 64 + c];
    }
    __syncthreads();
    int tl = threadIdx.x & 63;
    int g = __builtin_amdgcn_readfirstlane((int)(threadIdx.x >> 6));
    float acc[64];
#pragma unroll
    for (int o = 0; o < 64; o++) acc[o] = 0.f;
    for (int i = 0; i < 64; i++) {
        float xv = Q[i * 64 + tl];
        const float* wr = wt + i * 256 + g * 64;
#pragma unroll
        for (int o = 0; o < 64; o++) acc[o] = fmaf(wr[o], xv, acc[o]);
    }
#pragma unroll
    for (int o = 0; o < 64; o++) {
        int oc = g * 64 + o;
        out[(size_t)b * 131072 + (size_t)oc * 512 + l0 + tl] = acc[o] + bias[oc];
    }
}

// ---------------------------------------------------------------------------
extern "C" void kernel_launch(void* const* d_in, const int* in_sizes, int n_in,
                              void* d_out, int out_size, void* d_ws, size_t ws_size,
                              hipStream_t stream) {
    (void)in_sizes; (void)n_in; (void)out_size; (void)ws_size;
    const float* x          = (const float*)d_in[0];
    const float* in_np      = (const float*)d_in[1];
    const int*   mel2ph     = (const int*)d_in[2];
    const float* ph_np      = (const float*)d_in[3];
    const float* conv_in_w  = (const float*)d_in[4];
    const float* conv_in_b  = (const float*)d_in[5];
    const float* e_ln_g = (const float*)d_in[6];
    const float* e_ln_b = (const float*)d_in[7];
    const float* e_w1   = (const float*)d_in[8];
    const float* e_b1   = (const float*)d_in[9];
    const float* e_w2   = (const float*)d_in[10];
    const float* e_b2   = (const float*)d_in[11];
    const float* e_lg   = (const float*)d_in[12];
    const float* e_lb   = (const float*)d_in[13];
    const float* e_pw   = (const float*)d_in[14];
    const float* e_pb   = (const float*)d_in[15];
    const float* p_ln_g = (const float*)d_in[16];
    const float* p_ln_b = (const float*)d_in[17];
    const float* p_w1   = (const float*)d_in[18];
    const float* p_b1   = (const float*)d_in[19];
    const float* p_w2   = (const float*)d_in[20];
    const float* p_b2   = (const float*)d_in[21];
    const float* p_lg   = (const float*)d_in[22];
    const float* p_lb   = (const float*)d_in[23];
    const float* p_pw   = (const float*)d_in[24];
    const float* p_pb   = (const float*)d_in[25];
    const float* proj_in_w  = (const float*)d_in[26];
    const float* proj_in_b  = (const float*)d_in[27];
    const float* proj_out_w = (const float*)d_in[28];
    const float* proj_out_b = (const float*)d_in[29];
    const float* codebook   = (const float*)d_in[30];
    float* out = (float*)d_out;

    float* ws = (float*)d_ws;
    float* A      = ws;                        // 8388608
    float* Bb     = A + 8388608;               // 8388608
    float* CINT   = Bb + 8388608;              // 20480
    float* PSTT_E = CINT + 20480;              // 196608
    float* PSTT_P = PSTT_E + 196608;           // 196608
    float* PINT   = PSTT_P + 196608;           // 16384
    float* POUTT  = PINT + 16384;              // 16384
    float* Z      = POUTT + 16384;             // 524288
    float* MM0    = Z + 524288;                // 32768
    float* IV0    = MM0 + 32768;               // 32768
    float* MM1    = IV0 + 32768;               // 32768
    float* IV1    = MM1 + 32768;               // 32768
    int*   CNT    = (int*)(IV1 + 32768);       // 8192
    int*   IDX    = CNT + 8192;                // 8192
    float* LOSS   = (float*)(IDX + 8192);      // 64 (aligned pad)
    u16*   BH1E   = (u16*)(LOSS + 64);         // 3932160 each
    u16*   BL1E   = BH1E + 3932160;
    u16*   BH1P   = BL1E + 3932160;
    u16*   BL1P   = BH1P + 3932160;
    u16*   BH2E   = BL1P + 3932160;            // 1310720 each
    u16*   BL2E   = BH2E + 1310720;
    u16*   BH2P   = BL2E + 1310720;
    u16*   BL2P   = BH2P + 1310720;

    // weight prep (ws re-poisoned every call -> recompute)
    k_t_w1mf<<<dim3(4096), dim3(256), 0, stream>>>(e_w1, BH1E, BL1E, 10);
    k_t_w1mf<<<dim3(4096), dim3(256), 0, stream>>>(p_w1, BH1P, BL1P, 10);
    k_t_w2mf<<<dim3(2048), dim3(256), 0, stream>>>(e_w2, BH2E, BL2E, 10);
    k_t_w2mf<<<dim3(2048), dim3(256), 0, stream>>>(p_w2, BH2P, BL2P, 10);
    k_t_mat  <<<dim3(80),  dim3(256), 0, stream>>>(conv_in_w, CINT, 1, 256, 80);
    k_t_conv3<<<dim3(768), dim3(256), 0, stream>>>(e_pw, PSTT_E, 1, 256, 256);
    k_t_conv3<<<dim3(768), dim3(256), 0, stream>>>(p_pw, PSTT_P, 1, 256, 256);
    k_t_mat  <<<dim3(64),  dim3(256), 0, stream>>>(proj_in_w, PINT, 1, 64, 256);
    k_t_mat  <<<dim3(64),  dim3(256), 0, stream>>>(proj_out_w, POUTT, 1, 256, 64);

    const size_t sm_scat = 256 * 65 * sizeof(float) + 64 * sizeof(int);

    // ---- conv_in + mask -> A (+ LN stats for encoder layer 0)
    k_pw<80, 256, 64, true><<<dim3(32, 16), dim3(256), 80 * 64 * 4, stream>>>(
        x, CINT, conv_in_b, in_np, A, MM0, IV0, 2048);

    // ---- encoder: 10 fused sub-blocks, ping-pong A<->B and MM0/1 (ends A/MM0)
    float* cur = A;
    float* nxt = Bb;
    for (int s = 0; s < 10; s++) {
        float* mi = (s & 1) ? MM1 : MM0;
        float* vi = (s & 1) ? IV1 : IV0;
        float* mo = (s & 1) ? MM0 : MM1;
        float* vo = (s & 1) ? IV0 : IV1;
        k_sub<<<dim3(32, 16), dim3(512), 0, stream>>>(
            cur, nxt, mi, vi, e_ln_g + s * 256, e_ln_b + s * 256,
            BH1E + (size_t)s * 393216, BL1E + (size_t)s * 393216, e_b1 + s * 512,
            BH2E + (size_t)s * 131072, BL2E + (size_t)s * 131072, e_b2 + s * 256,
            in_np, mo, vo, 2048);
        float* t = cur; cur = nxt; nxt = t;
    }
    // final stats are in MM0/IV0 (10 layers: last write was s=9 odd -> MM0)
    k_lnconv<<<dim3(32, 16), dim3(512), 0, stream>>>(
        cur, nxt, MM0, IV0, e_lg, e_lb, PSTT_E, e_pb, in_np, 2048);

    // ---- group-by-segs: B (T=2048) -> A (compact [16,256,512])
    hipMemsetAsync(A, 0, (size_t)2097152 * 4, stream);
    hipMemsetAsync(LOSS, 0, 4, stream);
    k_counts<<<dim3(16), dim3(256), 0, stream>>>(mel2ph, CNT);
    k_scatter<<<dim3(32, 16), dim3(256), sm_scat, stream>>>(Bb, mel2ph, A);
    k_postprep<<<dim3(16), dim3(512), 0, stream>>>(A, CNT, MM0, IV0);

    // ---- postnet: 10 fused sub-blocks on T=512
    cur = A; nxt = Bb;
    for (int s = 0; s < 10; s++) {
        float* mi = (s & 1) ? MM1 : MM0;
        float* vi = (s & 1) ? IV1 : IV0;
        float* mo = (s & 1) ? MM0 : MM1;
        float* vo = (s & 1) ? IV0 : IV1;
        k_sub<<<dim3(8, 16), dim3(512), 0, stream>>>(
            cur, nxt, mi, vi, p_ln_g + s * 256, p_ln_b + s * 256,
            BH1P + (size_t)s * 393216, BL1P + (size_t)s * 393216, p_b1 + s * 512,
            BH2P + (size_t)s * 131072, BL2P + (size_t)s * 131072, p_b2 + s * 256,
            ph_np, mo, vo, 512);
        float* t = cur; cur = nxt; nxt = t;
    }
    k_lnconv<<<dim3(8, 16), dim3(512), 0, stream>>>(
        cur, nxt, MM0, IV0, p_lg, p_lb, PSTT_P, p_pb, ph_np, 512);

    // ---- proj_in: B -> Z [16,64,512]
    k_pw<256, 64, 16, false><<<dim3(8, 16), dim3(256), 256 * 64 * 4, stream>>>(
        Bb, PINT, proj_in_b, nullptr, Z, nullptr, nullptr, 512);

    // ---- VQ + loss + proj_out
    k_vq<<<dim3(32), dim3(256), 0, stream>>>(Z, codebook, IDX, out, LOSS);
    k_loss<<<dim3(1), dim3(64), 0, stream>>>(LOSS, out);
    k_projout<<<dim3(8, 16), dim3(256), 0, stream>>>(codebook, IDX, POUTT,
                                                     proj_out_b, out);
}

// Round 9
// 3360.369 us; speedup vs baseline: 3.2324x; 1.1900x over previous
//
#include <hip/hip_runtime.h>
#include <hip/hip_bf16.h>

// ---------------------------------------------------------------------------
// StyleEncoder pipeline for MI355X (gfx950).  R9: fused sub-block with M=32
// tile (73 KB LDS -> 2 blocks/CU, was 140 KB/1) + split accumulator chains.
// Split-f16 MFMA (x=hi+lo, w=hi+lo, 3x mfma_f32_32x32x16_f16).
// All inputs fp32; d_out fp32: out @0, vq_loss @2097152, idx @2097153.
// ---------------------------------------------------------------------------

typedef unsigned short u16;
typedef unsigned int u32;
typedef __attribute__((ext_vector_type(8))) _Float16 f16x8;
typedef __attribute__((ext_vector_type(16))) float f32x16;

#define OUT_LOSS_OFF 2097152
#define OUT_IDX_OFF  2097153

__device__ __forceinline__ void split_f16(float x, u16& h, u16& l) {
    union { _Float16 f; u16 u; } a, b;
    a.f = (_Float16)x;              // RNE f32->f16
    float hf = (float)a.f;
    b.f = (_Float16)(x - hf);       // residual, RNE to f16
    h = a.u; l = b.u;
}

// ---------------- weight transposes (fp32 kept for lnconv/pw) ---------------
__global__ __launch_bounds__(256) void k_t_conv3(const float* __restrict__ w,
                                                 float* __restrict__ wt,
                                                 int G, int O, int Cin) {
    size_t n = (size_t)G * O * Cin * 3;
    for (size_t i = (size_t)blockIdx.x * 256 + threadIdx.x; i < n;
         i += (size_t)gridDim.x * 256) {
        int k = (int)(i % 3);
        size_t r = i / 3;
        int c = (int)(r % Cin); r /= Cin;
        int o = (int)(r % O);
        int g = (int)(r / O);
        wt[((size_t)g * Cin * 3 + (size_t)(c * 3 + k)) * O + o] = w[i];
    }
}

__global__ __launch_bounds__(256) void k_t_mat(const float* __restrict__ w,
                                               float* __restrict__ wt,
                                               int G, int O, int I) {
    size_t n = (size_t)G * O * I;
    for (size_t i = (size_t)blockIdx.x * 256 + threadIdx.x; i < n;
         i += (size_t)gridDim.x * 256) {
        int ci = (int)(i % I);
        int o  = (int)((i / I) % O);
        int g  = (int)(i / ((size_t)I * O));
        wt[((size_t)g * I + ci) * O + o] = w[i];
    }
}

// ---- W1 -> B-fragment layout, split hi/lo f16.
// idx = ((((s*3+k3)*16+kb)*16+nt)*64+L)*8+j ; val = w1[s][oc][c][k3]
// oc = nt*32+(L&31), c = kb*16+((L>>5)<<3)+j
__global__ __launch_bounds__(256) void k_t_w1mf(const float* __restrict__ w,
                                                u16* __restrict__ BH,
                                                u16* __restrict__ BL, int S) {
    size_t N = (size_t)S * 3 * 16 * 16 * 64 * 8;
    for (size_t i = (size_t)blockIdx.x * 256 + threadIdx.x; i < N;
         i += (size_t)gridDim.x * 256) {
        int j = (int)(i & 7); size_t r = i >> 3;
        int L = (int)(r & 63); r >>= 6;
        int nt = (int)(r & 15); r >>= 4;
        int kb = (int)(r & 15); r >>= 4;
        int k3 = (int)(r % 3); int s = (int)(r / 3);
        int oc = nt * 32 + (L & 31);
        int c = kb * 16 + ((L >> 5) << 3) + j;
        float v = w[(((size_t)s * 512 + oc) * 256 + c) * 3 + k3];
        u16 h, l; split_f16(v, h, l);
        BH[i] = h; BL[i] = l;
    }
}

// ---- W2 -> B-fragment layout. idx = (((s*32+kb)*8+nt)*64+L)*8+j
// val = w2[s][oc][ic], oc = nt*32+(L&31), ic = kb*16+((L>>5)<<3)+j
__global__ __launch_bounds__(256) void k_t_w2mf(const float* __restrict__ w,
                                                u16* __restrict__ BH,
                                                u16* __restrict__ BL, int S) {
    size_t N = (size_t)S * 32 * 8 * 64 * 8;
    for (size_t i = (size_t)blockIdx.x * 256 + threadIdx.x; i < N;
         i += (size_t)gridDim.x * 256) {
        int j = (int)(i & 7);
        int L = (int)((i >> 3) & 63);
        int nt = (int)((i >> 9) & 7);
        int kb = (int)((i >> 12) & 31);
        int s = (int)(i >> 17);
        int oc = nt * 32 + (L & 31);
        int ic = kb * 16 + ((L >> 5) << 3) + j;
        float v = w[((size_t)s * 256 + oc) * 512 + ic];
        u16 h, l; split_f16(v, h, l);
        BH[i] = h; BL[i] = l;
    }
}

// ---------------- pointwise conv (+ optional column stats) ------------------
template <int CIN, int COUT, int CHUNK, bool STATS>
__global__ __launch_bounds__(256) void k_pw(const float* __restrict__ x,
                                            const float* __restrict__ wt,
                                            const float* __restrict__ bias,
                                            const float* __restrict__ mask,
                                            float* __restrict__ y,
                                            float* __restrict__ MM,
                                            float* __restrict__ IV, int T) {
    extern __shared__ float X[];
    constexpr int NG = COUT / CHUNK;
    __shared__ float rs[64 * NG], rs2[64 * NG];
    const int b = blockIdx.y, t0 = blockIdx.x * 64;
    for (int i = threadIdx.x; i < CIN * 64; i += 256) {
        int ci = i >> 6, j = i & 63;
        X[i] = x[((size_t)b * CIN + ci) * T + t0 + j];
    }
    __syncthreads();
    const int tl = threadIdx.x & 63;
    const int g = __builtin_amdgcn_readfirstlane((int)(threadIdx.x >> 6));
    float acc[CHUNK];
#pragma unroll
    for (int o = 0; o < CHUNK; o++) acc[o] = 0.f;
    for (int i = 0; i < CIN; i++) {
        float xv = X[i * 64 + tl];
        const float* wr = wt + (size_t)i * COUT + g * CHUNK;
#pragma unroll
        for (int o = 0; o < CHUNK; o++) acc[o] = fmaf(wr[o], xv, acc[o]);
    }
    float mk = mask ? mask[(size_t)b * T + t0 + tl] : 1.0f;
    float s = 0.f, s2 = 0.f;
#pragma unroll
    for (int o = 0; o < CHUNK; o++) {
        int oc = g * CHUNK + o;
        float val = (acc[o] + bias[oc]) * mk;
        y[((size_t)b * COUT + oc) * T + t0 + tl] = val;
        s += val; s2 += val * val;
    }
    if constexpr (STATS) {
        rs[g * 64 + tl] = s; rs2[g * 64 + tl] = s2;
        __syncthreads();
        if (threadIdx.x < 64) {
            float ss = 0.f, ss2 = 0.f;
#pragma unroll
            for (int gg = 0; gg < NG; gg++) {
                ss += rs[gg * 64 + threadIdx.x];
                ss2 += rs2[gg * 64 + threadIdx.x];
            }
            float m = ss * (1.0f / COUT);
            float var = ss2 * (1.0f / COUT) - m * m;
            MM[(size_t)b * T + t0 + threadIdx.x] = m;
            IV[(size_t)b * T + t0 + threadIdx.x] = 1.0f / sqrtf(var + 1e-5f);
        }
    }
}

// ---------------- fused sub-block (M=32): LN->conv1->GELU->conv2->residual --
// 512 thr / 8 waves; wave w owns n-tile w. LDS 73 KB -> 2 blocks/CU.
// LH/LL: f16-split LN'd x [j 0..33][c 0..255] stride 264.
// G: packed gelu [t 0..31][oc_l 0..255] stride 260 (one 256-oc half at a time).
// MM/IV ping-pong (halo race across blocks otherwise).
__global__ __launch_bounds__(512, 4) void k_sub(
    const float* __restrict__ xin, float* __restrict__ xout,
    const float* __restrict__ MMi, const float* __restrict__ IVi,
    const float* __restrict__ lng, const float* __restrict__ lnb,
    const u16* __restrict__ B1H, const u16* __restrict__ B1L,
    const float* __restrict__ b1,
    const u16* __restrict__ B2H, const u16* __restrict__ B2L,
    const float* __restrict__ b2, const float* __restrict__ mask,
    float* __restrict__ MMo, float* __restrict__ IVo, int T) {
    __shared__ __align__(16) char smem[73280];
    u16* LH = (u16*)smem;                     // 34*264 u16 = 17952 B
    u16* LL = (u16*)(smem + 17952);           // 17952 B
    u32* G  = (u32*)(smem + 35904);           // 32*260 u32 = 33280 B
    float* SOUT = (float*)smem;               // overlay (32*260 f32 = 33280)
    float* rs  = (float*)(smem + 69184);      // 512 f32
    float* rs2 = (float*)(smem + 71232);      // 512 f32

    const int tid = threadIdx.x;
    const int b = blockIdx.y, t0 = blockIdx.x * 32;
    const size_t xoff = (size_t)b * 256 * T;
    const size_t bT = (size_t)b * T;

    // ---- stage: LN'd x, split hi/lo f16
    {
        int jj = tid & 31;            // row 0..31 (t = t0-2+jj)
        int cg = tid >> 5;            // 0..15
        int t = t0 - 2 + jj;
        bool ok = (t >= 0);
        float m = ok ? MMi[bT + t] : 0.f;
        float v = ok ? IVi[bT + t] : 0.f;
#pragma unroll
        for (int i = 0; i < 16; i++) {
            int c = cg + i * 16;
            float xv = ok ? xin[xoff + (size_t)c * T + t] : 0.f;
            float ln = ok ? ((xv - m) * v * lng[c] + lnb[c]) : 0.f;
            u16 h, l; split_f16(ln, h, l);
            LH[jj * 264 + c] = h; LL[jj * 264 + c] = l;
        }
        int j2 = 32 + (tid >> 8);     // rows 32,33
        int c2 = tid & 255;
        int t2 = t0 + 30 + (tid >> 8);
        float m2 = MMi[bT + t2], v2 = IVi[bT + t2];
        float x2 = xin[xoff + (size_t)c2 * T + t2];
        float ln2 = (x2 - m2) * v2 * lng[c2] + lnb[c2];
        u16 h2, l2; split_f16(ln2, h2, l2);
        LH[j2 * 264 + c2] = h2; LL[j2 * 264 + c2] = l2;
    }
    __syncthreads();

    const int lane = tid & 63;
    const int w = tid >> 6;           // wave id 0..7 = n-tile
    const int arow = lane & 31;
    const int acol = (lane >> 5) << 3;
    const int thalf = (lane >> 5) << 2;
    const float ks = 0.5773502691896258f;

    f32x16 c2H, c2M;                  // conv2 chains (persist across p)
#pragma unroll
    for (int r = 0; r < 16; r++) { c2H[r] = 0.f; c2M[r] = 0.f; }

    for (int p = 0; p < 2; p++) {
        // ---- conv1 half p: wave computes oc = p*256 + w*32 + (lane&31)
        f32x16 aH, aM;
#pragma unroll
        for (int r = 0; r < 16; r++) { aH[r] = 0.f; aM[r] = 0.f; }
        const int nt1 = p * 8 + w;
#pragma unroll
        for (int k3 = 0; k3 < 3; k3++) {
#pragma unroll
            for (int kb = 0; kb < 16; kb++) {
                int ao = (arow + k3) * 264 + kb * 16 + acol;
                f16x8 ah = *(const f16x8*)&LH[ao];
                f16x8 al = *(const f16x8*)&LL[ao];
                int kk = k3 * 16 + kb;
                size_t bi = ((size_t)(kk * 16 + nt1) * 64 + lane) * 8;
                f16x8 bh = *(const f16x8*)(B1H + bi);
                f16x8 bl = *(const f16x8*)(B1L + bi);
                aH = __builtin_amdgcn_mfma_f32_32x32x16_f16(ah, bh, aH, 0, 0, 0);
                aM = __builtin_amdgcn_mfma_f32_32x32x16_f16(ah, bl, aM, 0, 0, 0);
                aM = __builtin_amdgcn_mfma_f32_32x32x16_f16(al, bh, aM, 0, 0, 0);
            }
        }
        __syncthreads();  // prior-G readers done (p=1); no-op cost at p=0
        // ---- gelu + pack -> G[t][oc_l]
        {
            int oc_l = w * 32 + (lane & 31);
            float bb = b1[p * 256 + oc_l];
#pragma unroll
            for (int r = 0; r < 16; r++) {
                int trow = thalf + ((r >> 2) << 3) + (r & 3);
                float y = (aH[r] + aM[r] + bb) * ks;
                float ge = 0.5f * y * (1.0f + erff(y * 0.7071067811865476f));
                u16 h, l; split_f16(ge, h, l);
                G[trow * 260 + oc_l] = ((u32)h << 16) | (u32)l;
            }
        }
        __syncthreads();
        // ---- conv2 partial: K chunk = 256 oc of half p
        const int grow = (lane & 31) * 260;
#pragma unroll
        for (int kb = 0; kb < 16; kb++) {
            const u32* gp = &G[grow + kb * 16 + acol];
            uint4 p0 = *(const uint4*)gp;
            uint4 p1 = *(const uint4*)(gp + 4);
            union { f16x8 v; u32 u[4]; } ah, al;
            ah.u[0] = __builtin_amdgcn_perm(p0.y, p0.x, 0x07060302u);
            al.u[0] = __builtin_amdgcn_perm(p0.y, p0.x, 0x05040100u);
            ah.u[1] = __builtin_amdgcn_perm(p0.w, p0.z, 0x07060302u);
            al.u[1] = __builtin_amdgcn_perm(p0.w, p0.z, 0x05040100u);
            ah.u[2] = __builtin_amdgcn_perm(p1.y, p1.x, 0x07060302u);
            al.u[2] = __builtin_amdgcn_perm(p1.y, p1.x, 0x05040100u);
            ah.u[3] = __builtin_amdgcn_perm(p1.w, p1.z, 0x07060302u);
            al.u[3] = __builtin_amdgcn_perm(p1.w, p1.z, 0x05040100u);
            int kbg = p * 16 + kb;
            size_t bi = ((size_t)(kbg * 8 + w) * 64 + lane) * 8;
            f16x8 bh = *(const f16x8*)(B2H + bi);
            f16x8 bl = *(const f16x8*)(B2L + bi);
            c2H = __builtin_amdgcn_mfma_f32_32x32x16_f16(ah.v, bh, c2H, 0, 0, 0);
            c2M = __builtin_amdgcn_mfma_f32_32x32x16_f16(ah.v, bl, c2M, 0, 0, 0);
            c2M = __builtin_amdgcn_mfma_f32_32x32x16_f16(al.v, bh, c2M, 0, 0, 0);
        }
        __syncthreads();  // G consumed before next pack / SOUT overlay
    }
    // ---- epilogue: transpose via SOUT (overlays LH/LL; all LH reads done)
    {
        int oc = w * 32 + (lane & 31);
#pragma unroll
        for (int r = 0; r < 16; r++) {
            int trow = thalf + ((r >> 2) << 3) + (r & 3);
            SOUT[trow * 260 + oc] = c2H[r] + c2M[r];
        }
    }
    __syncthreads();
    {
        int t = tid & 31, cg = tid >> 5;
        float mk = mask[bT + t0 + t];
        float s = 0.f, s2 = 0.f;
#pragma unroll
        for (int i = 0; i < 16; i++) {
            int c = cg * 16 + i;
            size_t adr = xoff + (size_t)c * T + t0 + t;
            float val = (xin[adr] + SOUT[t * 260 + c] + b2[c]) * mk;
            xout[adr] = val;
            s += val; s2 += val * val;
        }
        rs[tid] = s; rs2[tid] = s2;
    }
    __syncthreads();
    if (tid < 32) {
        float ss = 0.f, ss2 = 0.f;
#pragma unroll
        for (int k = 0; k < 16; k++) {
            ss += rs[k * 32 + tid]; ss2 += rs2[k * 32 + tid];
        }
        float m = ss * (1.0f / 256.0f);
        float var = ss2 * (1.0f / 256.0f) - m * m;
        MMo[bT + t0 + tid] = m;
        IVo[bT + t0 + tid] = 1.0f / sqrtf(var + 1e-5f);
    }
}

// ---------------- final LN*mask + causal conv (k=3, 256->256), fp32 ---------
__global__ __launch_bounds__(512, 8) void k_lnconv(
    const float* __restrict__ xin, float* __restrict__ xout,
    const float* __restrict__ MM, const float* __restrict__ IV,
    const float* __restrict__ lg, const float* __restrict__ lb,
    const float* __restrict__ wt, const float* __restrict__ bias,
    const float* __restrict__ mask, int T) {
    __shared__ float CH[128 * 66];
    __shared__ float sm_m[66], sm_v[66], sm_k[66];
    const int b = blockIdx.y, t0 = blockIdx.x * 64;
    const size_t xoff = (size_t)b * 256 * T;
    if (threadIdx.x < 66) {
        int t = t0 - 2 + (int)threadIdx.x;
        sm_m[threadIdx.x] = (t >= 0) ? MM[(size_t)b * T + t] : 0.f;
        sm_v[threadIdx.x] = (t >= 0) ? IV[(size_t)b * T + t] : 0.f;
        sm_k[threadIdx.x] = (t >= 0) ? mask[(size_t)b * T + t] : 0.f;
    }
    const int tl = threadIdx.x & 63;
    const int g = __builtin_amdgcn_readfirstlane((int)(threadIdx.x >> 6));
    float acc[32];
#pragma unroll
    for (int o = 0; o < 32; o++) acc[o] = 0.f;
    const float* wp = wt + g * 32;

    for (int ch = 0; ch < 2; ch++) {
        __syncthreads();
        for (int i = threadIdx.x; i < 128 * 66; i += 512) {
            int c = i / 66, j = i - c * 66;
            int t = t0 - 2 + j;
            int cc = ch * 128 + c;
            float val = 0.f;
            if (t >= 0)
                val = ((xin[xoff + (size_t)cc * T + t] - sm_m[j]) * sm_v[j] *
                           lg[cc] + lb[cc]) * sm_k[j];
            CH[i] = val;
        }
        __syncthreads();
        for (int c = 0; c < 128; ++c) {
#pragma unroll
            for (int k = 0; k < 3; ++k) {
                float xv = CH[c * 66 + tl + k];
                const float* wr = wp + (size_t)((ch * 128 + c) * 3 + k) * 256;
#pragma unroll
                for (int o = 0; o < 32; o++) acc[o] = fmaf(wr[o], xv, acc[o]);
            }
        }
    }
    float mk = mask[(size_t)b * T + t0 + tl];
#pragma unroll
    for (int o = 0; o < 32; o++) {
        int oc = g * 32 + o;
        xout[xoff + (size_t)oc * T + t0 + tl] = (acc[o] + bias[oc]) * mk;
    }
}

// ---------------- group-by-segments (scatter mean) --------------------------
__global__ __launch_bounds__(256) void k_counts(const int* __restrict__ m2p,
                                                int* __restrict__ cnt) {
    __shared__ int c[512];
    int b = blockIdx.x;
    for (int i = threadIdx.x; i < 512; i += 256) c[i] = 0;
    __syncthreads();
    for (int t = threadIdx.x; t < 2048; t += 256) {
        int p = m2p[b * 2048 + t];
        if (p >= 1 && p <= 512) atomicAdd(&c[p - 1], 1);
    }
    __syncthreads();
    for (int i = threadIdx.x; i < 512; i += 256) cnt[b * 512 + i] = c[i];
}

__global__ __launch_bounds__(256) void k_scatter(const float* __restrict__ h,
                                                 const int* __restrict__ m2p,
                                                 float* __restrict__ g) {
    extern __shared__ float sm[];
    float* HT = sm;
    int* ph = (int*)(sm + 256 * 65);
    int b = blockIdx.y, t0 = blockIdx.x * 64;
    if (threadIdx.x < 64) ph[threadIdx.x] = m2p[b * 2048 + t0 + threadIdx.x];
    for (int i = threadIdx.x; i < 256 * 64; i += 256) {
        int c = i >> 6, j = i & 63;
        HT[c * 65 + j] = h[((size_t)b * 256 + c) * 2048 + t0 + j];
    }
    __syncthreads();
    int c = threadIdx.x;
    float run = 0.f;
    int cur = ph[0];
    for (int j = 0; j < 64; j++) {
        int p = ph[j];
        if (p != cur) {
            if (cur >= 1 && cur <= 512)
                atomicAdd(&g[((size_t)b * 256 + c) * 512 + cur - 1], run);
            run = 0.f;
            cur = p;
        }
        run += HT[c * 65 + j];
    }
    if (cur >= 1 && cur <= 512)
        atomicAdd(&g[((size_t)b * 256 + c) * 512 + cur - 1], run);
}

__global__ __launch_bounds__(512) void k_postprep(float* __restrict__ g,
                                                  const int* __restrict__ cnt,
                                                  float* __restrict__ MM,
                                                  float* __restrict__ IV) {
    int b = blockIdx.x, l = threadIdx.x;
    int c1 = cnt[b * 512 + l];
    if (c1 < 1) c1 = 1;
    float rc = 1.0f / (float)c1;
    float s = 0.f, s2 = 0.f;
    for (int c = 0; c < 256; c++) {
        size_t idx = ((size_t)b * 256 + c) * 512 + l;
        float v = g[idx] * rc;
        g[idx] = v;
        s += v; s2 += v * v;
    }
    float m = s * (1.0f / 256.0f);
    float var = s2 * (1.0f / 256.0f) - m * m;
    MM[(size_t)b * 512 + l] = m;
    IV[(size_t)b * 512 + l] = 1.0f / sqrtf(var + 1e-5f);
}

// ---------------- VQ --------------------------------------------------------
__global__ __launch_bounds__(256) void k_vq(const float* __restrict__ z,
                                            const float* __restrict__ cb,
                                            int* __restrict__ idxout,
                                            float* __restrict__ out,
                                            float* __restrict__ lossacc) {
    int n = blockIdx.x * 256 + threadIdx.x;
    int b = n >> 9, l = n & 511;
    float zr[64];
#pragma unroll
    for (int c = 0; c < 64; c++) zr[c] = z[((size_t)b * 64 + c) * 512 + l];
    float best = 3.4e38f;
    int bi = 0;
    for (int k = 0; k < 128; k++) {
        const float* cr = cb + k * 64;
        float d = 0.f;
#pragma unroll
        for (int c = 0; c < 64; c++) {
            float t = zr[c] - cr[c];
            d = fmaf(t, t, d);
        }
        if (d < best) { best = d; bi = k; }
    }
    idxout[n] = bi;
    out[OUT_IDX_OFF + n] = (float)bi;
    atomicAdd(lossacc, best);
}

__global__ void k_loss(const float* __restrict__ acc, float* __restrict__ out) {
    if (threadIdx.x == 0 && blockIdx.x == 0)
        out[OUT_LOSS_OFF] = 0.25f * acc[0] * (1.0f / 524288.0f);
}

// ---------------- proj_out --------------------------------------------------
__global__ __launch_bounds__(256) void k_projout(const float* __restrict__ cb,
                                                 const int* __restrict__ idx,
                                                 const float* __restrict__ wt,
                                                 const float* __restrict__ bias,
                                                 float* __restrict__ out) {
    __shared__ float Q[64 * 64];
    __shared__ int ids[64];
    int b = blockIdx.y, l0 = blockIdx.x * 64;
    if (threadIdx.x < 64) ids[threadIdx.x] = idx[b * 512 + l0 + threadIdx.x];
    __syncthreads();
    for (int i = threadIdx.x; i < 4096; i += 256) {
        int c = i >> 6, l = i & 63;
        Q[c * 64 + l] = cb[ids[l] * 64 + c];
    }
    __syncthreads();
    int tl = threadIdx.x & 63;
    int g = __builtin_amdgcn_readfirstlane((int)(threadIdx.x >> 6));
    float acc[64];
#pragma unroll
    for (int o = 0; o < 64; o++) acc[o] = 0.f;
    for (int i = 0; i < 64; i++) {
        float xv = Q[i * 64 + tl];
        const float* wr = wt + i * 256 + g * 64;
#pragma unroll
        for (int o = 0; o < 64; o++) acc[o] = fmaf(wr[o], xv, acc[o]);
    }
#pragma unroll
    for (int o = 0; o < 64; o++) {
        int oc = g * 64 + o;
        out[(size_t)b * 131072 + (size_t)oc * 512 + l0 + tl] = acc[o] + bias[oc];
    }
}

// ---------------------------------------------------------------------------
extern "C" void kernel_launch(void* const* d_in, const int* in_sizes, int n_in,
                              void* d_out, int out_size, void* d_ws, size_t ws_size,
                              hipStream_t stream) {
    (void)in_sizes; (void)n_in; (void)out_size; (void)ws_size;
    const float* x          = (const float*)d_in[0];
    const float* in_np      = (const float*)d_in[1];
    const int*   mel2ph     = (const int*)d_in[2];
    const float* ph_np      = (const float*)d_in[3];
    const float* conv_in_w  = (const float*)d_in[4];
    const float* conv_in_b  = (const float*)d_in[5];
    const float* e_ln_g = (const float*)d_in[6];
    const float* e_ln_b = (const float*)d_in[7];
    const float* e_w1   = (const float*)d_in[8];
    const float* e_b1   = (const float*)d_in[9];
    const float* e_w2   = (const float*)d_in[10];
    const float* e_b2   = (const float*)d_in[11];
    const float* e_lg   = (const float*)d_in[12];
    const float* e_lb   = (const float*)d_in[13];
    const float* e_pw   = (const float*)d_in[14];
    const float* e_pb   = (const float*)d_in[15];
    const float* p_ln_g = (const float*)d_in[16];
    const float* p_ln_b = (const float*)d_in[17];
    const float* p_w1   = (const float*)d_in[18];
    const float* p_b1   = (const float*)d_in[19];
    const float* p_w2   = (const float*)d_in[20];
    const float* p_b2   = (const float*)d_in[21];
    const float* p_lg   = (const float*)d_in[22];
    const float* p_lb   = (const float*)d_in[23];
    const float* p_pw   = (const float*)d_in[24];
    const float* p_pb   = (const float*)d_in[25];
    const float* proj_in_w  = (const float*)d_in[26];
    const float* proj_in_b  = (const float*)d_in[27];
    const float* proj_out_w = (const float*)d_in[28];
    const float* proj_out_b = (const float*)d_in[29];
    const float* codebook   = (const float*)d_in[30];
    float* out = (float*)d_out;

    float* ws = (float*)d_ws;
    float* A      = ws;                        // 8388608
    float* Bb     = A + 8388608;               // 8388608
    float* CINT   = Bb + 8388608;              // 20480
    float* PSTT_E = CINT + 20480;              // 196608
    float* PSTT_P = PSTT_E + 196608;           // 196608
    float* PINT   = PSTT_P + 196608;           // 16384
    float* POUTT  = PINT + 16384;              // 16384
    float* Z      = POUTT + 16384;             // 524288
    float* MM0    = Z + 524288;                // 32768
    float* IV0    = MM0 + 32768;               // 32768
    float* MM1    = IV0 + 32768;               // 32768
    float* IV1    = MM1 + 32768;               // 32768
    int*   CNT    = (int*)(IV1 + 32768);       // 8192
    int*   IDX    = CNT + 8192;                // 8192
    float* LOSS   = (float*)(IDX + 8192);      // 64 (aligned pad)
    u16*   BH1E   = (u16*)(LOSS + 64);         // 3932160 each
    u16*   BL1E   = BH1E + 3932160;
    u16*   BH1P   = BL1E + 3932160;
    u16*   BL1P   = BH1P + 3932160;
    u16*   BH2E   = BL1P + 3932160;            // 1310720 each
    u16*   BL2E   = BH2E + 1310720;
    u16*   BH2P   = BL2E + 1310720;
    u16*   BL2P   = BH2P + 1310720;

    // weight prep (ws re-poisoned every call -> recompute)
    k_t_w1mf<<<dim3(4096), dim3(256), 0, stream>>>(e_w1, BH1E, BL1E, 10);
    k_t_w1mf<<<dim3(4096), dim3(256), 0, stream>>>(p_w1, BH1P, BL1P, 10);
    k_t_w2mf<<<dim3(2048), dim3(256), 0, stream>>>(e_w2, BH2E, BL2E, 10);
    k_t_w2mf<<<dim3(2048), dim3(256), 0, stream>>>(p_w2, BH2P, BL2P, 10);
    k_t_mat  <<<dim3(80),  dim3(256), 0, stream>>>(conv_in_w, CINT, 1, 256, 80);
    k_t_conv3<<<dim3(768), dim3(256), 0, stream>>>(e_pw, PSTT_E, 1, 256, 256);
    k_t_conv3<<<dim3(768), dim3(256), 0, stream>>>(p_pw, PSTT_P, 1, 256, 256);
    k_t_mat  <<<dim3(64),  dim3(256), 0, stream>>>(proj_in_w, PINT, 1, 64, 256);
    k_t_mat  <<<dim3(64),  dim3(256), 0, stream>>>(proj_out_w, POUTT, 1, 256, 64);

    const size_t sm_scat = 256 * 65 * sizeof(float) + 64 * sizeof(int);

    // ---- conv_in + mask -> A (+ LN stats for encoder layer 0)
    k_pw<80, 256, 64, true><<<dim3(32, 16), dim3(256), 80 * 64 * 4, stream>>>(
        x, CINT, conv_in_b, in_np, A, MM0, IV0, 2048);

    // ---- encoder: 10 fused sub-blocks, ping-pong A<->B and MM0/1
    float* cur = A;
    float* nxt = Bb;
    for (int s = 0; s < 10; s++) {
        float* mi = (s & 1) ? MM1 : MM0;
        float* vi = (s & 1) ? IV1 : IV0;
        float* mo = (s & 1) ? MM0 : MM1;
        float* vo = (s & 1) ? IV0 : IV1;
        k_sub<<<dim3(64, 16), dim3(512), 0, stream>>>(
            cur, nxt, mi, vi, e_ln_g + s * 256, e_ln_b + s * 256,
            BH1E + (size_t)s * 393216, BL1E + (size_t)s * 393216, e_b1 + s * 512,
            BH2E + (size_t)s * 131072, BL2E + (size_t)s * 131072, e_b2 + s * 256,
            in_np, mo, vo, 2048);
        float* t = cur; cur = nxt; nxt = t;
    }
    // final stats in MM0/IV0 (s=9 odd -> wrote MM0)
    k_lnconv<<<dim3(32, 16), dim3(512), 0, stream>>>(
        cur, nxt, MM0, IV0, e_lg, e_lb, PSTT_E, e_pb, in_np, 2048);

    // ---- group-by-segs: B (T=2048) -> A (compact [16,256,512])
    hipMemsetAsync(A, 0, (size_t)2097152 * 4, stream);
    hipMemsetAsync(LOSS, 0, 4, stream);
    k_counts<<<dim3(16), dim3(256), 0, stream>>>(mel2ph, CNT);
    k_scatter<<<dim3(32, 16), dim3(256), sm_scat, stream>>>(Bb, mel2ph, A);
    k_postprep<<<dim3(16), dim3(512), 0, stream>>>(A, CNT, MM0, IV0);

    // ---- postnet: 10 fused sub-blocks on T=512
    cur = A; nxt = Bb;
    for (int s = 0; s < 10; s++) {
        float* mi = (s & 1) ? MM1 : MM0;
        float* vi = (s & 1) ? IV1 : IV0;
        float* mo = (s & 1) ? MM0 : MM1;
        float* vo = (s & 1) ? IV0 : IV1;
        k_sub<<<dim3(16, 16), dim3(512), 0, stream>>>(
            cur, nxt, mi, vi, p_ln_g + s * 256, p_ln_b + s * 256,
            BH1P + (size_t)s * 393216, BL1P + (size_t)s * 393216, p_b1 + s * 512,
            BH2P + (size_t)s * 131072, BL2P + (size_t)s * 131072, p_b2 + s * 256,
            ph_np, mo, vo, 512);
        float* t = cur; cur = nxt; nxt = t;
    }
    k_lnconv<<<dim3(8, 16), dim3(512), 0, stream>>>(
        cur, nxt, MM0, IV0, p_lg, p_lb, PSTT_P, p_pb, ph_np, 512);

    // ---- proj_in: B -> Z [16,64,512]
    k_pw<256, 64, 16, false><<<dim3(8, 16), dim3(256), 256 * 64 * 4, stream>>>(
        Bb, PINT, proj_in_b, nullptr, Z, nullptr, nullptr, 512);

    // ---- VQ + loss + proj_out
    k_vq<<<dim3(32), dim3(256), 0, stream>>>(Z, codebook, IDX, out, LOSS);
    k_loss<<<dim3(1), dim3(64), 0, stream>>>(LOSS, out);
    k_projout<<<dim3(8, 16), dim3(256), 0, stream>>>(codebook, IDX, POUTT,
                                                     proj_out_b, out);
}

// Round 10
// 2325.608 us; speedup vs baseline: 4.6706x; 1.4449x over previous
//
#include <hip/hip_runtime.h>
#include <hip/hip_bf16.h>

// ---------------------------------------------------------------------------
// StyleEncoder pipeline for MI355X (gfx950).  R10:
//  - k_sub: merged phase (conv2-p0 MFMA interleaved with conv1-p1 MFMA),
//    barriers 7->6, two independent MFMA chains in the merged phase.
//  - k_lnconv -> k_lnc: final LN+causal-conv as split-f16 MFMA GEMM
//    (36 KB LDS -> 4 blocks/CU).
// Split-f16 MFMA everywhere (x=hi+lo, w=hi+lo, 3x mfma_f32_32x32x16_f16).
// All inputs fp32; d_out fp32: out @0, vq_loss @2097152, idx @2097153.
// ---------------------------------------------------------------------------

typedef unsigned short u16;
typedef unsigned int u32;
typedef __attribute__((ext_vector_type(8))) _Float16 f16x8;
typedef __attribute__((ext_vector_type(16))) float f32x16;

#define OUT_LOSS_OFF 2097152
#define OUT_IDX_OFF  2097153

__device__ __forceinline__ void split_f16(float x, u16& h, u16& l) {
    union { _Float16 f; u16 u; } a, b;
    a.f = (_Float16)x;              // RNE f32->f16
    float hf = (float)a.f;
    b.f = (_Float16)(x - hf);       // residual, RNE to f16
    h = a.u; l = b.u;
}

// ---------------- weight transposes -----------------------------------------
__global__ __launch_bounds__(256) void k_t_mat(const float* __restrict__ w,
                                               float* __restrict__ wt,
                                               int G, int O, int I) {
    size_t n = (size_t)G * O * I;
    for (size_t i = (size_t)blockIdx.x * 256 + threadIdx.x; i < n;
         i += (size_t)gridDim.x * 256) {
        int ci = (int)(i % I);
        int o  = (int)((i / I) % O);
        int g  = (int)(i / ((size_t)I * O));
        wt[((size_t)g * I + ci) * O + o] = w[i];
    }
}

// ---- W1 -> B-fragment layout, split hi/lo f16.
// idx = ((((s*3+k3)*16+kb)*16+nt)*64+L)*8+j ; val = w1[s][oc][c][k3]
// oc = nt*32+(L&31), c = kb*16+((L>>5)<<3)+j
__global__ __launch_bounds__(256) void k_t_w1mf(const float* __restrict__ w,
                                                u16* __restrict__ BH,
                                                u16* __restrict__ BL, int S) {
    size_t N = (size_t)S * 3 * 16 * 16 * 64 * 8;
    for (size_t i = (size_t)blockIdx.x * 256 + threadIdx.x; i < N;
         i += (size_t)gridDim.x * 256) {
        int j = (int)(i & 7); size_t r = i >> 3;
        int L = (int)(r & 63); r >>= 6;
        int nt = (int)(r & 15); r >>= 4;
        int kb = (int)(r & 15); r >>= 4;
        int k3 = (int)(r % 3); int s = (int)(r / 3);
        int oc = nt * 32 + (L & 31);
        int c = kb * 16 + ((L >> 5) << 3) + j;
        float v = w[(((size_t)s * 512 + oc) * 256 + c) * 3 + k3];
        u16 h, l; split_f16(v, h, l);
        BH[i] = h; BL[i] = l;
    }
}

// ---- W2 -> B-fragment layout. idx = (((s*32+kb)*8+nt)*64+L)*8+j
__global__ __launch_bounds__(256) void k_t_w2mf(const float* __restrict__ w,
                                                u16* __restrict__ BH,
                                                u16* __restrict__ BL, int S) {
    size_t N = (size_t)S * 32 * 8 * 64 * 8;
    for (size_t i = (size_t)blockIdx.x * 256 + threadIdx.x; i < N;
         i += (size_t)gridDim.x * 256) {
        int j = (int)(i & 7);
        int L = (int)((i >> 3) & 63);
        int nt = (int)((i >> 9) & 7);
        int kb = (int)((i >> 12) & 31);
        int s = (int)(i >> 17);
        int oc = nt * 32 + (L & 31);
        int ic = kb * 16 + ((L >> 5) << 3) + j;
        float v = w[((size_t)s * 256 + oc) * 512 + ic];
        u16 h, l; split_f16(v, h, l);
        BH[i] = h; BL[i] = l;
    }
}

// ---- post conv W [256 oc][256 c][3 k3] -> B-frag (O=256, K=768).
// idx = (((k3*16+kb)*8+nt)*64+L)*8+j ; oc = nt*32+(L&31), c = kb*16+((L>>5)<<3)+j
__global__ __launch_bounds__(256) void k_t_wpmf(const float* __restrict__ w,
                                                u16* __restrict__ BH,
                                                u16* __restrict__ BL) {
    int i = blockIdx.x * 256 + threadIdx.x;   // N = 196608, grid 768
    int j = i & 7;
    int L = (i >> 3) & 63;
    int nt = (i >> 9) & 7;
    int kb = (i >> 12) & 15;
    int k3 = i >> 16;
    int oc = nt * 32 + (L & 31);
    int c = kb * 16 + ((L >> 5) << 3) + j;
    float v = w[((size_t)oc * 256 + c) * 3 + k3];
    u16 h, l; split_f16(v, h, l);
    BH[i] = h; BL[i] = l;
}

// ---------------- pointwise conv (+ optional column stats) ------------------
template <int CIN, int COUT, int CHUNK, bool STATS>
__global__ __launch_bounds__(256) void k_pw(const float* __restrict__ x,
                                            const float* __restrict__ wt,
                                            const float* __restrict__ bias,
                                            const float* __restrict__ mask,
                                            float* __restrict__ y,
                                            float* __restrict__ MM,
                                            float* __restrict__ IV, int T) {
    extern __shared__ float X[];
    constexpr int NG = COUT / CHUNK;
    __shared__ float rs[64 * NG], rs2[64 * NG];
    const int b = blockIdx.y, t0 = blockIdx.x * 64;
    for (int i = threadIdx.x; i < CIN * 64; i += 256) {
        int ci = i >> 6, j = i & 63;
        X[i] = x[((size_t)b * CIN + ci) * T + t0 + j];
    }
    __syncthreads();
    const int tl = threadIdx.x & 63;
    const int g = __builtin_amdgcn_readfirstlane((int)(threadIdx.x >> 6));
    float acc[CHUNK];
#pragma unroll
    for (int o = 0; o < CHUNK; o++) acc[o] = 0.f;
    for (int i = 0; i < CIN; i++) {
        float xv = X[i * 64 + tl];
        const float* wr = wt + (size_t)i * COUT + g * CHUNK;
#pragma unroll
        for (int o = 0; o < CHUNK; o++) acc[o] = fmaf(wr[o], xv, acc[o]);
    }
    float mk = mask ? mask[(size_t)b * T + t0 + tl] : 1.0f;
    float s = 0.f, s2 = 0.f;
#pragma unroll
    for (int o = 0; o < CHUNK; o++) {
        int oc = g * CHUNK + o;
        float val = (acc[o] + bias[oc]) * mk;
        y[((size_t)b * COUT + oc) * T + t0 + tl] = val;
        s += val; s2 += val * val;
    }
    if constexpr (STATS) {
        rs[g * 64 + tl] = s; rs2[g * 64 + tl] = s2;
        __syncthreads();
        if (threadIdx.x < 64) {
            float ss = 0.f, ss2 = 0.f;
#pragma unroll
            for (int gg = 0; gg < NG; gg++) {
                ss += rs[gg * 64 + threadIdx.x];
                ss2 += rs2[gg * 64 + threadIdx.x];
            }
            float m = ss * (1.0f / COUT);
            float var = ss2 * (1.0f / COUT) - m * m;
            MM[(size_t)b * T + t0 + threadIdx.x] = m;
            IV[(size_t)b * T + t0 + threadIdx.x] = 1.0f / sqrtf(var + 1e-5f);
        }
    }
}

// ---------------- fused sub-block (M=32), merged-phase version --------------
// 512 thr / 8 waves; wave w owns n-tile w. LDS 73 KB -> 2 blocks/CU.
// Phases: stage | conv1p0 | pack0 | [conv2p0 x conv1p1 interleaved] | pack1 |
//         conv2p1 | epilogue.  6 barriers.
__global__ __launch_bounds__(512, 4) void k_sub(
    const float* __restrict__ xin, float* __restrict__ xout,
    const float* __restrict__ MMi, const float* __restrict__ IVi,
    const float* __restrict__ lng, const float* __restrict__ lnb,
    const u16* __restrict__ B1H, const u16* __restrict__ B1L,
    const float* __restrict__ b1,
    const u16* __restrict__ B2H, const u16* __restrict__ B2L,
    const float* __restrict__ b2, const float* __restrict__ mask,
    float* __restrict__ MMo, float* __restrict__ IVo, int T) {
    __shared__ __align__(16) char smem[73280];
    u16* LH = (u16*)smem;                     // 34*264 u16 = 17952 B
    u16* LL = (u16*)(smem + 17952);           // 17952 B
    u32* G  = (u32*)(smem + 35904);           // 32*260 u32 = 33280 B
    float* SOUT = (float*)smem;               // overlay (33280 <= 35904)
    float* rs  = (float*)(smem + 69184);      // 512 f32
    float* rs2 = (float*)(smem + 71232);      // 512 f32

    const int tid = threadIdx.x;
    const int b = blockIdx.y, t0 = blockIdx.x * 32;
    const size_t xoff = (size_t)b * 256 * T;
    const size_t bT = (size_t)b * T;

    // ---- stage: LN'd x, split hi/lo f16
    {
        int jj = tid & 31;
        int cg = tid >> 5;
        int t = t0 - 2 + jj;
        bool ok = (t >= 0);
        float m = ok ? MMi[bT + t] : 0.f;
        float v = ok ? IVi[bT + t] : 0.f;
#pragma unroll
        for (int i = 0; i < 16; i++) {
            int c = cg + i * 16;
            float xv = ok ? xin[xoff + (size_t)c * T + t] : 0.f;
            float ln = ok ? ((xv - m) * v * lng[c] + lnb[c]) : 0.f;
            u16 h, l; split_f16(ln, h, l);
            LH[jj * 264 + c] = h; LL[jj * 264 + c] = l;
        }
        int j2 = 32 + (tid >> 8);
        int c2 = tid & 255;
        int t2 = t0 + 30 + (tid >> 8);
        float m2 = MMi[bT + t2], v2 = IVi[bT + t2];
        float x2 = xin[xoff + (size_t)c2 * T + t2];
        float ln2 = (x2 - m2) * v2 * lng[c2] + lnb[c2];
        u16 h2, l2; split_f16(ln2, h2, l2);
        LH[j2 * 264 + c2] = h2; LL[j2 * 264 + c2] = l2;
    }
    __syncthreads();                                   // (1)

    const int lane = tid & 63;
    const int w = tid >> 6;
    const int arow = lane & 31;
    const int acol = (lane >> 5) << 3;
    const int thalf = (lane >> 5) << 2;
    const float ks = 0.5773502691896258f;
    const int oc_l = w * 32 + (lane & 31);
    const u16* b1h0 = B1H + (size_t)w * 512 + (size_t)lane * 8;        // nt=w
    const u16* b1l0 = B1L + (size_t)w * 512 + (size_t)lane * 8;
    const u16* b1h1 = B1H + (size_t)(8 + w) * 512 + (size_t)lane * 8;  // nt=8+w
    const u16* b1l1 = B1L + (size_t)(8 + w) * 512 + (size_t)lane * 8;
    const u16* b2h = B2H + (size_t)w * 512 + (size_t)lane * 8;
    const u16* b2l = B2L + (size_t)w * 512 + (size_t)lane * 8;
    const int grow = (lane & 31) * 260;

    f32x16 c2H, c2M;
#pragma unroll
    for (int r = 0; r < 16; r++) { c2H[r] = 0.f; c2M[r] = 0.f; }

    // ---- phase A: conv1 p=0
    f32x16 aH, aM;
#pragma unroll
    for (int r = 0; r < 16; r++) { aH[r] = 0.f; aM[r] = 0.f; }
#pragma unroll
    for (int kk = 0; kk < 48; kk++) {
        int k3 = kk >> 4, kb = kk & 15;
        int ao = (arow + k3) * 264 + kb * 16 + acol;
        f16x8 ah = *(const f16x8*)&LH[ao];
        f16x8 al = *(const f16x8*)&LL[ao];
        f16x8 bh = *(const f16x8*)(b1h0 + (size_t)kk * 8192);
        f16x8 bl = *(const f16x8*)(b1l0 + (size_t)kk * 8192);
        aH = __builtin_amdgcn_mfma_f32_32x32x16_f16(ah, bh, aH, 0, 0, 0);
        aM = __builtin_amdgcn_mfma_f32_32x32x16_f16(ah, bl, aM, 0, 0, 0);
        aM = __builtin_amdgcn_mfma_f32_32x32x16_f16(al, bh, aM, 0, 0, 0);
    }
    // ---- pack p0 (G has no prior readers: no pre-sync needed)
    {
        float bb = b1[oc_l];
#pragma unroll
        for (int r = 0; r < 16; r++) {
            int trow = thalf + ((r >> 2) << 3) + (r & 3);
            float y = (aH[r] + aM[r] + bb) * ks;
            float ge = 0.5f * y * (1.0f + erff(y * 0.7071067811865476f));
            u16 h, l; split_f16(ge, h, l);
            G[trow * 260 + oc_l] = ((u32)h << 16) | (u32)l;
        }
    }
    __syncthreads();                                   // (2) G p0 visible

    // ---- phase B: conv2 p0 interleaved with conv1 p1 (independent chains)
#pragma unroll
    for (int r = 0; r < 16; r++) { aH[r] = 0.f; aM[r] = 0.f; }
    for (int i = 0; i < 16; i++) {
#pragma unroll
        for (int t3 = 0; t3 < 3; t3++) {
            int kk = i * 3 + t3;
            int k3 = kk >> 4, kb = kk & 15;
            int ao = (arow + k3) * 264 + kb * 16 + acol;
            f16x8 ah = *(const f16x8*)&LH[ao];
            f16x8 al = *(const f16x8*)&LL[ao];
            f16x8 bh = *(const f16x8*)(b1h1 + (size_t)kk * 8192);
            f16x8 bl = *(const f16x8*)(b1l1 + (size_t)kk * 8192);
            aH = __builtin_amdgcn_mfma_f32_32x32x16_f16(ah, bh, aH, 0, 0, 0);
            aM = __builtin_amdgcn_mfma_f32_32x32x16_f16(ah, bl, aM, 0, 0, 0);
            aM = __builtin_amdgcn_mfma_f32_32x32x16_f16(al, bh, aM, 0, 0, 0);
        }
        {
            const u32* gp = &G[grow + i * 16 + acol];
            uint4 p0 = *(const uint4*)gp;
            uint4 p1 = *(const uint4*)(gp + 4);
            union { f16x8 v; u32 u[4]; } gh, gl;
            gh.u[0] = __builtin_amdgcn_perm(p0.y, p0.x, 0x07060302u);
            gl.u[0] = __builtin_amdgcn_perm(p0.y, p0.x, 0x05040100u);
            gh.u[1] = __builtin_amdgcn_perm(p0.w, p0.z, 0x07060302u);
            gl.u[1] = __builtin_amdgcn_perm(p0.w, p0.z, 0x05040100u);
            gh.u[2] = __builtin_amdgcn_perm(p1.y, p1.x, 0x07060302u);
            gl.u[2] = __builtin_amdgcn_perm(p1.y, p1.x, 0x05040100u);
            gh.u[3] = __builtin_amdgcn_perm(p1.w, p1.z, 0x07060302u);
            gl.u[3] = __builtin_amdgcn_perm(p1.w, p1.z, 0x05040100u);
            f16x8 bh = *(const f16x8*)(b2h + (size_t)i * 4096);
            f16x8 bl = *(const f16x8*)(b2l + (size_t)i * 4096);
            c2H = __builtin_amdgcn_mfma_f32_32x32x16_f16(gh.v, bh, c2H, 0, 0, 0);
            c2M = __builtin_amdgcn_mfma_f32_32x32x16_f16(gh.v, bl, c2M, 0, 0, 0);
            c2M = __builtin_amdgcn_mfma_f32_32x32x16_f16(gl.v, bh, c2M, 0, 0, 0);
        }
    }
    __syncthreads();                                   // (3) G+LH/LL reads done
    // ---- pack p1
    {
        float bb = b1[256 + oc_l];
#pragma unroll
        for (int r = 0; r < 16; r++) {
            int trow = thalf + ((r >> 2) << 3) + (r & 3);
            float y = (aH[r] + aM[r] + bb) * ks;
            float ge = 0.5f * y * (1.0f + erff(y * 0.7071067811865476f));
            u16 h, l; split_f16(ge, h, l);
            G[trow * 260 + oc_l] = ((u32)h << 16) | (u32)l;
        }
    }
    __syncthreads();                                   // (4) G p1 visible

    // ---- phase C: conv2 p1
    for (int i = 0; i < 16; i++) {
        const u32* gp = &G[grow + i * 16 + acol];
        uint4 p0 = *(const uint4*)gp;
        uint4 p1 = *(const uint4*)(gp + 4);
        union { f16x8 v; u32 u[4]; } gh, gl;
        gh.u[0] = __builtin_amdgcn_perm(p0.y, p0.x, 0x07060302u);
        gl.u[0] = __builtin_amdgcn_perm(p0.y, p0.x, 0x05040100u);
        gh.u[1] = __builtin_amdgcn_perm(p0.w, p0.z, 0x07060302u);
        gl.u[1] = __builtin_amdgcn_perm(p0.w, p0.z, 0x05040100u);
        gh.u[2] = __builtin_amdgcn_perm(p1.y, p1.x, 0x07060302u);
        gl.u[2] = __builtin_amdgcn_perm(p1.y, p1.x, 0x05040100u);
        gh.u[3] = __builtin_amdgcn_perm(p1.w, p1.z, 0x07060302u);
        gl.u[3] = __builtin_amdgcn_perm(p1.w, p1.z, 0x05040100u);
        f16x8 bh = *(const f16x8*)(b2h + (size_t)(16 + i) * 4096);
        f16x8 bl = *(const f16x8*)(b2l + (size_t)(16 + i) * 4096);
        c2H = __builtin_amdgcn_mfma_f32_32x32x16_f16(gh.v, bh, c2H, 0, 0, 0);
        c2M = __builtin_amdgcn_mfma_f32_32x32x16_f16(gh.v, bl, c2M, 0, 0, 0);
        c2M = __builtin_amdgcn_mfma_f32_32x32x16_f16(gl.v, bh, c2M, 0, 0, 0);
    }
    // ---- SOUT writes (disjoint from G; LH/LL dead since barrier 3)
#pragma unroll
    for (int r = 0; r < 16; r++) {
        int trow = thalf + ((r >> 2) << 3) + (r & 3);
        SOUT[trow * 260 + oc_l] = c2H[r] + c2M[r];
    }
    __syncthreads();                                   // (5)
    {
        int t = tid & 31, cg = tid >> 5;
        float mk = mask[bT + t0 + t];
        float s = 0.f, s2 = 0.f;
#pragma unroll
        for (int i = 0; i < 16; i++) {
            int c = cg * 16 + i;
            size_t adr = xoff + (size_t)c * T + t0 + t;
            float val = (xin[adr] + SOUT[t * 260 + c] + b2[c]) * mk;
            xout[adr] = val;
            s += val; s2 += val * val;
        }
        rs[tid] = s; rs2[tid] = s2;
    }
    __syncthreads();                                   // (6)
    if (tid < 32) {
        float ss = 0.f, ss2 = 0.f;
#pragma unroll
        for (int k = 0; k < 16; k++) {
            ss += rs[k * 32 + tid]; ss2 += rs2[k * 32 + tid];
        }
        float m = ss * (1.0f / 256.0f);
        float var = ss2 * (1.0f / 256.0f) - m * m;
        MMo[bT + t0 + tid] = m;
        IVo[bT + t0 + tid] = 1.0f / sqrtf(var + 1e-5f);
    }
}

// ---------------- final LN*mask + causal conv via MFMA ----------------------
// M=32 tile, N=256 (8 waves x 1 n-tile), K=768. LDS 36 KB -> 4 blocks/CU.
__global__ __launch_bounds__(512, 8) void k_lnc(
    const float* __restrict__ xin, float* __restrict__ xout,
    const float* __restrict__ MM, const float* __restrict__ IV,
    const float* __restrict__ lg, const float* __restrict__ lb,
    const u16* __restrict__ BH, const u16* __restrict__ BL,
    const float* __restrict__ bias, const float* __restrict__ mask, int T) {
    __shared__ __align__(16) char smem[35904];
    u16* LH = (u16*)smem;                 // 34*264 u16
    u16* LL = (u16*)(smem + 17952);
    float* SOUT = (float*)smem;           // overlay (33280 <= 35904)

    const int tid = threadIdx.x;
    const int b = blockIdx.y, t0 = blockIdx.x * 32;
    const size_t xoff = (size_t)b * 256 * T;
    const size_t bT = (size_t)b * T;

    {   // stage: (LN(x)*mask) hi/lo
        int jj = tid & 31;
        int cg = tid >> 5;
        int t = t0 - 2 + jj;
        bool ok = (t >= 0);
        float m = ok ? MM[bT + t] : 0.f;
        float v = ok ? IV[bT + t] : 0.f;
        float mk = ok ? mask[bT + t] : 0.f;
#pragma unroll
        for (int i = 0; i < 16; i++) {
            int c = cg + i * 16;
            float xv = ok ? xin[xoff + (size_t)c * T + t] : 0.f;
            float ln = ok ? ((xv - m) * v * lg[c] + lb[c]) * mk : 0.f;
            u16 h, l; split_f16(ln, h, l);
            LH[jj * 264 + c] = h; LL[jj * 264 + c] = l;
        }
        int j2 = 32 + (tid >> 8);
        int c2 = tid & 255;
        int t2 = t0 + 30 + (tid >> 8);
        float ln2 = ((xin[xoff + (size_t)c2 * T + t2] - MM[bT + t2]) *
                     IV[bT + t2] * lg[c2] + lb[c2]) * mask[bT + t2];
        u16 h2, l2; split_f16(ln2, h2, l2);
        LH[j2 * 264 + c2] = h2; LL[j2 * 264 + c2] = l2;
    }
    __syncthreads();

    const int lane = tid & 63;
    const int w = tid >> 6;
    const int arow = lane & 31;
    const int acol = (lane >> 5) << 3;
    const int thalf = (lane >> 5) << 2;
    const u16* bph = BH + (size_t)w * 512 + (size_t)lane * 8;
    const u16* bpl = BL + (size_t)w * 512 + (size_t)lane * 8;

    f32x16 aH, aM;
#pragma unroll
    for (int r = 0; r < 16; r++) { aH[r] = 0.f; aM[r] = 0.f; }
    for (int kk = 0; kk < 48; kk++) {
        int k3 = kk >> 4, kb = kk & 15;
        int ao = (arow + k3) * 264 + kb * 16 + acol;
        f16x8 ah = *(const f16x8*)&LH[ao];
        f16x8 al = *(const f16x8*)&LL[ao];
        f16x8 bh = *(const f16x8*)(bph + (size_t)kk * 4096);
        f16x8 bl = *(const f16x8*)(bpl + (size_t)kk * 4096);
        aH = __builtin_amdgcn_mfma_f32_32x32x16_f16(ah, bh, aH, 0, 0, 0);
        aM = __builtin_amdgcn_mfma_f32_32x32x16_f16(ah, bl, aM, 0, 0, 0);
        aM = __builtin_amdgcn_mfma_f32_32x32x16_f16(al, bh, aM, 0, 0, 0);
    }
    __syncthreads();  // all LH/LL reads done before SOUT overlay
    {
        int oc = w * 32 + (lane & 31);
#pragma unroll
        for (int r = 0; r < 16; r++) {
            int trow = thalf + ((r >> 2) << 3) + (r & 3);
            SOUT[trow * 260 + oc] = aH[r] + aM[r];
        }
    }
    __syncthreads();
    {
        int t = tid & 31, cg = tid >> 5;
        float mk = mask[bT + t0 + t];
#pragma unroll
        for (int i = 0; i < 16; i++) {
            int c = cg * 16 + i;
            xout[xoff + (size_t)c * T + t0 + t] =
                (SOUT[t * 260 + c] + bias[c]) * mk;
        }
    }
}

// ---------------- group-by-segments (scatter mean) --------------------------
__global__ __launch_bounds__(256) void k_counts(const int* __restrict__ m2p,
                                                int* __restrict__ cnt) {
    __shared__ int c[512];
    int b = blockIdx.x;
    for (int i = threadIdx.x; i < 512; i += 256) c[i] = 0;
    __syncthreads();
    for (int t = threadIdx.x; t < 2048; t += 256) {
        int p = m2p[b * 2048 + t];
        if (p >= 1 && p <= 512) atomicAdd(&c[p - 1], 1);
    }
    __syncthreads();
    for (int i = threadIdx.x; i < 512; i += 256) cnt[b * 512 + i] = c[i];
}

__global__ __launch_bounds__(256) void k_scatter(const float* __restrict__ h,
                                                 const int* __restrict__ m2p,
                                                 float* __restrict__ g) {
    extern __shared__ float sm[];
    float* HT = sm;
    int* ph = (int*)(sm + 256 * 65);
    int b = blockIdx.y, t0 = blockIdx.x * 64;
    if (threadIdx.x < 64) ph[threadIdx.x] = m2p[b * 2048 + t0 + threadIdx.x];
    for (int i = threadIdx.x; i < 256 * 64; i += 256) {
        int c = i >> 6, j = i & 63;
        HT[c * 65 + j] = h[((size_t)b * 256 + c) * 2048 + t0 + j];
    }
    __syncthreads();
    int c = threadIdx.x;
    float run = 0.f;
    int cur = ph[0];
    for (int j = 0; j < 64; j++) {
        int p = ph[j];
        if (p != cur) {
            if (cur >= 1 && cur <= 512)
                atomicAdd(&g[((size_t)b * 256 + c) * 512 + cur - 1], run);
            run = 0.f;
            cur = p;
        }
        run += HT[c * 65 + j];
    }
    if (cur >= 1 && cur <= 512)
        atomicAdd(&g[((size_t)b * 256 + c) * 512 + cur - 1], run);
}

__global__ __launch_bounds__(512) void k_postprep(float* __restrict__ g,
                                                  const int* __restrict__ cnt,
                                                  float* __restrict__ MM,
                                                  float* __restrict__ IV) {
    int b = blockIdx.x, l = threadIdx.x;
    int c1 = cnt[b * 512 + l];
    if (c1 < 1) c1 = 1;
    float rc = 1.0f / (float)c1;
    float s = 0.f, s2 = 0.f;
    for (int c = 0; c < 256; c++) {
        size_t idx = ((size_t)b * 256 + c) * 512 + l;
        float v = g[idx] * rc;
        g[idx] = v;
        s += v; s2 += v * v;
    }
    float m = s * (1.0f / 256.0f);
    float var = s2 * (1.0f / 256.0f) - m * m;
    MM[(size_t)b * 512 + l] = m;
    IV[(size_t)b * 512 + l] = 1.0f / sqrtf(var + 1e-5f);
}

// ---------------- VQ --------------------------------------------------------
__global__ __launch_bounds__(256) void k_vq(const float* __restrict__ z,
                                            const float* __restrict__ cb,
                                            int* __restrict__ idxout,
                                            float* __restrict__ out,
                                            float* __restrict__ lossacc) {
    int n = blockIdx.x * 256 + threadIdx.x;
    int b = n >> 9, l = n & 511;
    float zr[64];
#pragma unroll
    for (int c = 0; c < 64; c++) zr[c] = z[((size_t)b * 64 + c) * 512 + l];
    float best = 3.4e38f;
    int bi = 0;
    for (int k = 0; k < 128; k++) {
        const float* cr = cb + k * 64;
        float d = 0.f;
#pragma unroll
        for (int c = 0; c < 64; c++) {
            float t = zr[c] - cr[c];
            d = fmaf(t, t, d);
        }
        if (d < best) { best = d; bi = k; }
    }
    idxout[n] = bi;
    out[OUT_IDX_OFF + n] = (float)bi;
    atomicAdd(lossacc, best);
}

__global__ void k_loss(const float* __restrict__ acc, float* __restrict__ out) {
    if (threadIdx.x == 0 && blockIdx.x == 0)
        out[OUT_LOSS_OFF] = 0.25f * acc[0] * (1.0f / 524288.0f);
}

// ---------------- proj_out --------------------------------------------------
__global__ __launch_bounds__(256) void k_projout(const float* __restrict__ cb,
                                                 const int* __restrict__ idx,
                                                 const float* __restrict__ wt,
                                                 const float* __restrict__ bias,
                                                 float* __restrict__ out) {
    __shared__ float Q[64 * 64];
    __shared__ int ids[64];
    int b = blockIdx.y, l0 = blockIdx.x * 64;
    if (threadIdx.x < 64) ids[threadIdx.x] = idx[b * 512 + l0 + threadIdx.x];
    __syncthreads();
    for (int i = threadIdx.x; i < 4096; i += 256) {
        int c = i >> 6, l = i & 63;
        Q[c * 64 + l] = cb[ids[l] * 64 + c];
    }
    __syncthreads();
    int tl = threadIdx.x & 63;
    int g = __builtin_amdgcn_readfirstlane((int)(threadIdx.x >> 6));
    float acc[64];
#pragma unroll
    for (int o = 0; o < 64; o++) acc[o] = 0.f;
    for (int i = 0; i < 64; i++) {
        float xv = Q[i * 64 + tl];
        const float* wr = wt + i * 256 + g * 64;
#pragma unroll
        for (int o = 0; o < 64; o++) acc[o] = fmaf(wr[o], xv, acc[o]);
    }
#pragma unroll
    for (int o = 0; o < 64; o++) {
        int oc = g * 64 + o;
        out[(size_t)b * 131072 + (size_t)oc * 512 + l0 + tl] = acc[o] + bias[oc];
    }
}

// ---------------------------------------------------------------------------
extern "C" void kernel_launch(void* const* d_in, const int* in_sizes, int n_in,
                              void* d_out, int out_size, void* d_ws, size_t ws_size,
                              hipStream_t stream) {
    (void)in_sizes; (void)n_in; (void)out_size; (void)ws_size;
    const float* x          = (const float*)d_in[0];
    const float* in_np      = (const float*)d_in[1];
    const int*   mel2ph     = (const int*)d_in[2];
    const float* ph_np      = (const float*)d_in[3];
    const float* conv_in_w  = (const float*)d_in[4];
    const float* conv_in_b  = (const float*)d_in[5];
    const float* e_ln_g = (const float*)d_in[6];
    const float* e_ln_b = (const float*)d_in[7];
    const float* e_w1   = (const float*)d_in[8];
    const float* e_b1   = (const float*)d_in[9];
    const float* e_w2   = (const float*)d_in[10];
    const float* e_b2   = (const float*)d_in[11];
    const float* e_lg   = (const float*)d_in[12];
    const float* e_lb   = (const float*)d_in[13];
    const float* e_pw   = (const float*)d_in[14];
    const float* e_pb   = (const float*)d_in[15];
    const float* p_ln_g = (const float*)d_in[16];
    const float* p_ln_b = (const float*)d_in[17];
    const float* p_w1   = (const float*)d_in[18];
    const float* p_b1   = (const float*)d_in[19];
    const float* p_w2   = (const float*)d_in[20];
    const float* p_b2   = (const float*)d_in[21];
    const float* p_lg   = (const float*)d_in[22];
    const float* p_lb   = (const float*)d_in[23];
    const float* p_pw   = (const float*)d_in[24];
    const float* p_pb   = (const float*)d_in[25];
    const float* proj_in_w  = (const float*)d_in[26];
    const float* proj_in_b  = (const float*)d_in[27];
    const float* proj_out_w = (const float*)d_in[28];
    const float* proj_out_b = (const float*)d_in[29];
    const float* codebook   = (const float*)d_in[30];
    float* out = (float*)d_out;

    float* ws = (float*)d_ws;
    float* A      = ws;                        // 8388608
    float* Bb     = A + 8388608;               // 8388608
    float* CINT   = Bb + 8388608;              // 20480
    float* PINT   = CINT + 20480;              // 16384
    float* POUTT  = PINT + 16384;              // 16384
    float* Z      = POUTT + 16384;             // 524288
    float* MM0    = Z + 524288;                // 32768
    float* IV0    = MM0 + 32768;               // 32768
    float* MM1    = IV0 + 32768;               // 32768
    float* IV1    = MM1 + 32768;               // 32768
    int*   CNT    = (int*)(IV1 + 32768);       // 8192
    int*   IDX    = CNT + 8192;                // 8192
    float* LOSS   = (float*)(IDX + 8192);      // 64 (aligned pad)
    u16*   BH1E   = (u16*)(LOSS + 64);         // 3932160 each
    u16*   BL1E   = BH1E + 3932160;
    u16*   BH1P   = BL1E + 3932160;
    u16*   BL1P   = BH1P + 3932160;
    u16*   BH2E   = BL1P + 3932160;            // 1310720 each
    u16*   BL2E   = BH2E + 1310720;
    u16*   BH2P   = BL2E + 1310720;
    u16*   BL2P   = BH2P + 1310720;
    u16*   PH_E   = BL2P + 1310720;            // 196608 each
    u16*   PL_E   = PH_E + 196608;
    u16*   PH_P   = PL_E + 196608;
    u16*   PL_P   = PH_P + 196608;

    // weight prep (ws re-poisoned every call -> recompute)
    k_t_w1mf<<<dim3(4096), dim3(256), 0, stream>>>(e_w1, BH1E, BL1E, 10);
    k_t_w1mf<<<dim3(4096), dim3(256), 0, stream>>>(p_w1, BH1P, BL1P, 10);
    k_t_w2mf<<<dim3(2048), dim3(256), 0, stream>>>(e_w2, BH2E, BL2E, 10);
    k_t_w2mf<<<dim3(2048), dim3(256), 0, stream>>>(p_w2, BH2P, BL2P, 10);
    k_t_wpmf<<<dim3(768),  dim3(256), 0, stream>>>(e_pw, PH_E, PL_E);
    k_t_wpmf<<<dim3(768),  dim3(256), 0, stream>>>(p_pw, PH_P, PL_P);
    k_t_mat  <<<dim3(80),  dim3(256), 0, stream>>>(conv_in_w, CINT, 1, 256, 80);
    k_t_mat  <<<dim3(64),  dim3(256), 0, stream>>>(proj_in_w, PINT, 1, 64, 256);
    k_t_mat  <<<dim3(64),  dim3(256), 0, stream>>>(proj_out_w, POUTT, 1, 256, 64);

    const size_t sm_scat = 256 * 65 * sizeof(float) + 64 * sizeof(int);

    // ---- conv_in + mask -> A (+ LN stats for encoder layer 0)
    k_pw<80, 256, 64, true><<<dim3(32, 16), dim3(256), 80 * 64 * 4, stream>>>(
        x, CINT, conv_in_b, in_np, A, MM0, IV0, 2048);

    // ---- encoder: 10 fused sub-blocks, ping-pong A<->B and MM0/1
    float* cur = A;
    float* nxt = Bb;
    for (int s = 0; s < 10; s++) {
        float* mi = (s & 1) ? MM1 : MM0;
        float* vi = (s & 1) ? IV1 : IV0;
        float* mo = (s & 1) ? MM0 : MM1;
        float* vo = (s & 1) ? IV0 : IV1;
        k_sub<<<dim3(64, 16), dim3(512), 0, stream>>>(
            cur, nxt, mi, vi, e_ln_g + s * 256, e_ln_b + s * 256,
            BH1E + (size_t)s * 393216, BL1E + (size_t)s * 393216, e_b1 + s * 512,
            BH2E + (size_t)s * 131072, BL2E + (size_t)s * 131072, e_b2 + s * 256,
            in_np, mo, vo, 2048);
        float* t = cur; cur = nxt; nxt = t;
    }
    // final stats in MM0/IV0 (s=9 odd -> wrote MM0)
    k_lnc<<<dim3(64, 16), dim3(512), 0, stream>>>(
        cur, nxt, MM0, IV0, e_lg, e_lb, PH_E, PL_E, e_pb, in_np, 2048);

    // ---- group-by-segs: B (T=2048) -> A (compact [16,256,512])
    hipMemsetAsync(A, 0, (size_t)2097152 * 4, stream);
    hipMemsetAsync(LOSS, 0, 4, stream);
    k_counts<<<dim3(16), dim3(256), 0, stream>>>(mel2ph, CNT);
    k_scatter<<<dim3(32, 16), dim3(256), sm_scat, stream>>>(Bb, mel2ph, A);
    k_postprep<<<dim3(16), dim3(512), 0, stream>>>(A, CNT, MM0, IV0);

    // ---- postnet: 10 fused sub-blocks on T=512
    cur = A; nxt = Bb;
    for (int s = 0; s < 10; s++) {
        float* mi = (s & 1) ? MM1 : MM0;
        float* vi = (s & 1) ? IV1 : IV0;
        float* mo = (s & 1) ? MM0 : MM1;
        float* vo = (s & 1) ? IV0 : IV1;
        k_sub<<<dim3(16, 16), dim3(512), 0, stream>>>(
            cur, nxt, mi, vi, p_ln_g + s * 256, p_ln_b + s * 256,
            BH1P + (size_t)s * 393216, BL1P + (size_t)s * 393216, p_b1 + s * 512,
            BH2P + (size_t)s * 131072, BL2P + (size_t)s * 131072, p_b2 + s * 256,
            ph_np, mo, vo, 512);
        float* t = cur; cur = nxt; nxt = t;
    }
    k_lnc<<<dim3(16, 16), dim3(512), 0, stream>>>(
        cur, nxt, MM0, IV0, p_lg, p_lb, PH_P, PL_P, p_pb, ph_np, 512);

    // ---- proj_in: B -> Z [16,64,512]
    k_pw<256, 64, 16, false><<<dim3(8, 16), dim3(256), 256 * 64 * 4, stream>>>(
        Bb, PINT, proj_in_b, nullptr, Z, nullptr, nullptr, 512);

    // ---- VQ + loss + proj_out
    k_vq<<<dim3(32), dim3(256), 0, stream>>>(Z, codebook, IDX, out, LOSS);
    k_loss<<<dim3(1), dim3(64), 0, stream>>>(LOSS, out);
    k_projout<<<dim3(8, 16), dim3(256), 0, stream>>>(codebook, IDX, POUTT,
                                                     proj_out_b, out);
}